// Round 12
// baseline (236.876 us; speedup 1.0000x reference)
//
#include <hip/hip_runtime.h>
#include <stdint.h>

typedef __bf16 bf16x8 __attribute__((ext_vector_type(8)));
typedef __bf16 bf16x2 __attribute__((ext_vector_type(2)));
typedef float  f32x4  __attribute__((ext_vector_type(4)));
typedef short  s16x8  __attribute__((ext_vector_type(8)));

__device__ inline unsigned short f2b(float f) {
  unsigned int u = __builtin_bit_cast(unsigned int, f);
  u += 0x7FFFu + ((u >> 16) & 1u);
  return (unsigned short)(u >> 16);
}
__device__ inline float b2f(unsigned short h) {
  unsigned int u = ((unsigned int)h) << 16;
  return __builtin_bit_cast(float, u);
}
// native pack: compiler emits v_cvt_pk_bf16_f32
__device__ inline unsigned int pkcvt(float a, float b) {
  bf16x2 t;
  t[0] = (__bf16)a;
  t[1] = (__bf16)b;
  return __builtin_bit_cast(unsigned int, t);
}
__device__ inline void gload_lds16(const void* g, void* l) {
  __builtin_amdgcn_global_load_lds(
      (const __attribute__((address_space(1))) unsigned int*)g,
      (__attribute__((address_space(3))) unsigned int*)l, 16, 0, 0);
}

// ---------------- elementwise f32 -> bf16 ----------------
__global__ void k_cvt_bf16(const float* __restrict__ in, unsigned short* __restrict__ out, int n4) {
  int i = blockIdx.x * blockDim.x + threadIdx.x;
  if (i < n4) {
    float4 v = ((const float4*)in)[i];
    ushort4 o;
    o.x = f2b(v.x); o.y = f2b(v.y); o.z = f2b(v.z); o.w = f2b(v.w);
    ((ushort4*)out)[i] = o;
  }
}

// ---------------- transpose f32 -> bf16 [N][K]; z=0: Wq|Wk|Wv concat, z=1: Wo ----------------
__global__ void k_transpose(const float* __restrict__ Wq, const float* __restrict__ Wk,
                            const float* __restrict__ Wv, const float* __restrict__ Wo,
                            unsigned short* __restrict__ dstQKV, unsigned short* __restrict__ dstO) {
  __shared__ float tile[32][33];
  int n0 = blockIdx.x * 32;
  int k0 = blockIdx.y * 32;
  const float* src; int ldn, noff, K;
  unsigned short* dst;
  if (blockIdx.z == 0) {
    K = 2048; dst = dstQKV;
    if (n0 < 2048)       { src = Wq; ldn = 2048; noff = n0; }
    else if (n0 < 2176)  { src = Wk; ldn = 128;  noff = n0 - 2048; }
    else                 { src = Wv; ldn = 128;  noff = n0 - 2176; }
  } else {
    if (n0 >= 2048) return;
    K = 2048; dst = dstO;
    src = Wo; ldn = 2048; noff = n0;
  }
  int tx = threadIdx.x & 31, ty = threadIdx.x >> 5;
  for (int yy = ty; yy < 32; yy += 8)
    tile[yy][tx] = src[(size_t)(k0 + yy) * ldn + noff + tx];
  __syncthreads();
  for (int yy = ty; yy < 32; yy += 8)
    dst[(size_t)(n0 + yy) * K + k0 + tx] = f2b(tile[tx][yy]);
}

// ---------------- bias concat [2304] ----------------
__global__ void k_bias_concat(const float* __restrict__ bq, const float* __restrict__ bk,
                              const float* __restrict__ bv, float* __restrict__ dst) {
  int i = blockIdx.x * 256 + threadIdx.x;
  if (i < 2304) dst[i] = (i < 2048) ? bq[i] : (i < 2176 ? bk[i - 2048] : bv[i - 2176]);
}

// ---------------- bf16 GEMM: C = A * Bt^T + bias ----------------
// 128x128 tile, BK=32, global_load_lds w16, 3-buffer ring, 2-deep prefetch.
template<int OUT_BF16>
__global__ __launch_bounds__(256)
void k_gemm_lds(const unsigned short* __restrict__ A, const unsigned short* __restrict__ Bt,
                const float* __restrict__ bias, void* __restrict__ Cout,
                int M, int N, int K) {
  __shared__ unsigned short As[3][4096];   // [buf][128*32] linear
  __shared__ unsigned short Bs[3][4096];
  const int tid  = threadIdx.x;
  const int lane = tid & 63, wid = tid >> 6;
  const int lr = lane & 15, lk = lane >> 4;
  const int wr = wid >> 1,  wc = wid & 1;
  const int mb = blockIdx.y * 128, nb = blockIdx.x * 128;

  const int srow = tid >> 2, scb = (tid & 3) * 8;
  const size_t gA = (size_t)(mb + srow) * K + scb;
  const size_t gB = (size_t)(nb + srow) * K + scb;
  const int ldso = wid * 512;

  f32x4 acc[4][4];
  #pragma unroll
  for (int i = 0; i < 4; ++i)
    #pragma unroll
    for (int j = 0; j < 4; ++j) acc[i][j] = (f32x4){0.f, 0.f, 0.f, 0.f};

  auto stage = [&](int buf, int kt) {
    const size_t ko = (size_t)kt * 32;
    gload_lds16(A  + gA + ko,                  &As[buf][ldso]);
    gload_lds16(A  + gA + 64 * (size_t)K + ko, &As[buf][2048 + ldso]);
    gload_lds16(Bt + gB + ko,                  &Bs[buf][ldso]);
    gload_lds16(Bt + gB + 64 * (size_t)K + ko, &Bs[buf][2048 + ldso]);
  };

  const int ktn = K >> 5;
  stage(0, 0);
  stage(1, 1);

  int cur = 0;
  #pragma unroll 1
  for (int kt = 0; kt < ktn; ++kt) {
    if (kt + 2 < ktn) {
      int nbuf = cur + 2; if (nbuf >= 3) nbuf -= 3;
      stage(nbuf, kt + 2);
      asm volatile("s_waitcnt vmcnt(8)" ::: "memory");
    } else if (kt + 1 < ktn) {
      asm volatile("s_waitcnt vmcnt(4)" ::: "memory");
    } else {
      asm volatile("s_waitcnt vmcnt(0)" ::: "memory");
    }
    __builtin_amdgcn_sched_barrier(0);
    __builtin_amdgcn_s_barrier();
    bf16x8 af[4], bfv[4];
    #pragma unroll
    for (int m = 0; m < 4; ++m)
      af[m]  = *(const bf16x8*)&As[cur][(wr * 64 + m * 16 + lr) * 32 + lk * 8];
    #pragma unroll
    for (int n = 0; n < 4; ++n)
      bfv[n] = *(const bf16x8*)&Bs[cur][(wc * 64 + n * 16 + lr) * 32 + lk * 8];
    #pragma unroll
    for (int m = 0; m < 4; ++m)
      #pragma unroll
      for (int n = 0; n < 4; ++n)
        acc[m][n] = __builtin_amdgcn_mfma_f32_16x16x32_bf16(af[m], bfv[n], acc[m][n], 0, 0, 0);
    __builtin_amdgcn_s_barrier();
    ++cur; if (cur == 3) cur = 0;
  }

  const int r0 = mb + wr * 64, c0 = nb + wc * 64;
  #pragma unroll
  for (int m = 0; m < 4; ++m) {
    #pragma unroll
    for (int n = 0; n < 4; ++n) {
      int col = c0 + n * 16 + lr;
      float bb = bias[col];
      #pragma unroll
      for (int r = 0; r < 4; ++r) {
        int row = r0 + m * 16 + lk * 4 + r;
        float v = acc[m][n][r] + bb;
        if (OUT_BF16) ((unsigned short*)Cout)[(size_t)row * N + col] = f2b(v);
        else          ((float*)Cout)[(size_t)row * N + col] = v;
      }
    }
  }
}

// ---------------- RoPE (q heads + k); q pre-scaled by 1/sqrt(D) ----------------
__global__ void k_rope(const unsigned short* __restrict__ qkv,
                       unsigned short* __restrict__ qr,
                       unsigned short* __restrict__ kr,
                       int S, int H) {
  int R = blockIdx.x * 4 + (threadIdx.x >> 6);
  int lane = threadIdx.x & 63;
  int per_b = S * (H + 1);
  int b = R / per_b;
  int rem = R - b * per_b;
  int s = rem / (H + 1);
  int j = rem - s * (H + 1);
  const unsigned short* src = qkv + (size_t)(b * S + s) * 2304 + (j < H ? j * 128 : 2048);
  float x1 = b2f(src[lane]);
  float x2 = b2f(src[lane + 64]);
  float invf = expf(-(float)lane * (9.210340371976184f / 64.0f));
  float ang = (float)s * invf;
  float c = cosf(ang), sn = sinf(ang);
  float o1 = x1 * c - x2 * sn;
  float o2 = x1 * sn + x2 * c;
  unsigned short* dst;
  if (j < H) {
    const float scale = 0.08838834764831845f;  // fold 1/sqrt(128) into q
    o1 *= scale; o2 *= scale;
    dst = qr + ((size_t)(b * H + j) * S + s) * 128;
  } else {
    dst = kr + ((size_t)(b * S) + s) * 128;
  }
  dst[lane]      = f2b(o1);
  dst[lane + 64] = f2b(o2);
}

// ---------------- V transpose ----------------
__global__ void k_vtrans(const unsigned short* __restrict__ qkv,
                         unsigned short* __restrict__ vt, int S) {
  __shared__ unsigned short tile[32][33];
  int b = blockIdx.z;
  int s0 = blockIdx.x * 32, d0 = blockIdx.y * 32;
  int tx = threadIdx.x & 31, ty = threadIdx.x >> 5;
  for (int yy = ty; yy < 32; yy += 8)
    tile[yy][tx] = qkv[(size_t)(b * S + s0 + yy) * 2304 + 2176 + d0 + tx];
  __syncthreads();
  for (int yy = ty; yy < 32; yy += 8)
    vt[((size_t)b * 128 + d0 + yy) * S + s0 + tx] = tile[tx][yy];
}

// ---------------- causal flash attention (fused balanced pair) ----------------
// Block = 512 thr (8 waves) per (b, h, pair x): tiles A=15-x (heavy), B=x (light).
// Group 0 (waves 0-3): A kv-tiles 0..16. Group 1 (waves 4-7): A kv 17..nh-1 then
// all of B -- exactly 17 iterations each (nh+nl = 34). No-max softmax partials
// are additive: A = G0 + G1 combined via LDS at end. Each group has its own
// 64KB staged K/V (dbuf); barriers block-wide, lockstep by construction.
// 256 blocks = 1/CU, 8 waves sustained, uniform duration.
__global__ __launch_bounds__(512, 2)
void k_attn(const unsigned short* __restrict__ qr,  // [B][H][S][128]
            const unsigned short* __restrict__ kr,  // [B][S][128]
            const unsigned short* __restrict__ vt,  // [B][128][S]
            unsigned short* __restrict__ attn_out,  // [B][S][2048]
            int S, int H) {
  const int b = blockIdx.z, h = blockIdx.y;
  const int xp = blockIdx.x;                  // 0..7
  const int qtA = 15 - xp;
  const int qb0A = qtA * 128, qb0B = xp * 128;
  const int nh = 2 * qtA + 2;                 // 18..32 kv-tiles for A
  const int tid = threadIdx.x, wid = tid >> 6, lane = tid & 63;
  const int grp = wid >> 2, w4 = wid & 3;
  const int lr = lane & 15, lk = lane >> 4;
  const int gtid = tid & 255;

  __shared__ __align__(16) char ldsbuf[131072];
  char* gbase = ldsbuf + grp * 65536;   // per-group: K buf0/1 @0/16K, V buf0/1 @32K/48K

  const char* kbyte = (const char*)(kr + (size_t)b * S * 128);
  const char* vbyte = (const char*)(vt + (size_t)b * 128 * S);
  const size_t vrow_bytes = (size_t)S * 2;

  // ---- q fragments (row stride 128!)
  bf16x8 aqA[2][4], aqB[2][4];
  {
    const unsigned short* qa = qr + ((size_t)(b * H + h) * S + qb0A + w4 * 32) * 128;
    #pragma unroll
    for (int g = 0; g < 2; ++g)
      #pragma unroll
      for (int kk = 0; kk < 4; ++kk)
        aqA[g][kk] = *(const bf16x8*)(qa + (size_t)(g * 16 + lr) * 128 + kk * 32 + lk * 8);
    if (grp == 1) {
      const unsigned short* qb = qr + ((size_t)(b * H + h) * S + qb0B + w4 * 32) * 128;
      #pragma unroll
      for (int g = 0; g < 2; ++g)
        #pragma unroll
        for (int kk = 0; kk < 4; ++kk)
          aqB[g][kk] = *(const bf16x8*)(qb + (size_t)(g * 16 + lr) * 128 + kk * 32 + lk * 8);
    }
  }

  f32x4 accA[2][8], accB[2][8];
  #pragma unroll
  for (int g = 0; g < 2; ++g)
    #pragma unroll
    for (int t = 0; t < 8; ++t) {
      accA[g][t] = (f32x4){0.f, 0.f, 0.f, 0.f};
      accB[g][t] = (f32x4){0.f, 0.f, 0.f, 0.f};
    }
  float lsA[2] = {0.f, 0.f}, lsB[2] = {0.f, 0.f};

  const int vsw = ((lr & 3) | ((lr >> 1) & 4)) << 4;
  int krow_[4], ksw_[4];
  #pragma unroll
  for (int m = 0; m < 4; ++m) {
    int row = ((m >> 1) << 5) + ((m & 1) << 2) + ((lr >> 2) << 3) + (lr & 3);
    krow_[m] = row;
    ksw_[m] = ((row & 3) | ((row >> 1) & 4)) << 4;
  }

  auto stage = [&](int buf, int kb) {
    const char* kg = kbyte + (size_t)kb * 256;
    #pragma unroll
    for (int r = 0; r < 4; ++r) {
      int row = (gtid >> 4) + r * 16;
      int sw = ((row & 3) | ((row >> 1) & 4)) << 4;
      const char* src = kg + row * 256 + (((gtid & 15) << 4) ^ sw);
      gload_lds16(src, (void*)(gbase + buf * 16384 + r * 4096 + w4 * 1024));
    }
    const char* vg = vbyte + (size_t)kb * 2;
    #pragma unroll
    for (int r = 0; r < 4; ++r) {
      int d = (gtid >> 3) + r * 32;
      int sw = ((d & 3) | ((d >> 1) & 4)) << 4;
      const char* src = vg + (size_t)d * vrow_bytes + (((gtid & 7) << 4) ^ sw);
      gload_lds16(src, (void*)(gbase + 32768 + buf * 16384 + r * 4096 + w4 * 1024));
    }
  };

  // schedule: iteration j -> (kb, which tile). G0: A tile j. G1: idx=17+j.
  auto itemKb = [&](int j, int& which) -> int {
    if (grp == 0) { which = 0; return j * 64; }
    int idx = 17 + j;
    if (idx < nh) { which = 0; return idx * 64; }
    which = 1; return (idx - nh) * 64;
  };

  auto computeTile = [&](const unsigned short* Kc, const unsigned short* Vc,
                         int kb, int qb0cur, bf16x8 (&aq)[2][4],
                         f32x4 (&acc)[2][8], float (&ls)[2]) {
    const int qw = qb0cur + w4 * 32;
    if (kb > qw + 31) return;
    // ---- QK^T both row groups, kf loaded per-kk, reused
    f32x4 s4[2][4];
    #pragma unroll
    for (int g = 0; g < 2; ++g)
      #pragma unroll
      for (int m = 0; m < 4; ++m) s4[g][m] = (f32x4){0.f, 0.f, 0.f, 0.f};
    __builtin_amdgcn_s_setprio(1);
    #pragma unroll
    for (int kk = 0; kk < 4; ++kk) {
      bf16x8 kfk[4];
      #pragma unroll
      for (int m = 0; m < 4; ++m)
        kfk[m] = *(const bf16x8*)((const char*)Kc + krow_[m] * 256 + ((kk * 64 + lk * 16) ^ ksw_[m]));
      #pragma unroll
      for (int m = 0; m < 4; ++m) {
        s4[0][m] = __builtin_amdgcn_mfma_f32_16x16x32_bf16(kfk[m], aq[0][kk], s4[0][m], 0, 0, 0);
        s4[1][m] = __builtin_amdgcn_mfma_f32_16x16x32_bf16(kfk[m], aq[1][kk], s4[1][m], 0, 0, 0);
      }
    }
    __builtin_amdgcn_s_setprio(0);
    // ---- exp, diag-range mask, lane-local pack
    bf16x8 pa[2][2];
    #pragma unroll
    for (int g = 0; g < 2; ++g) {
      const int rowq = qw + g * 16 + lr;
      const bool domask = (kb + 64) > (qw + g * 16);
      uint2 pk[4];
      #pragma unroll
      for (int m = 0; m < 4; ++m) {
        const int kb_m = kb + ((m >> 1) << 5) + ((m & 1) << 2) + lk * 8;
        float p[4];
        #pragma unroll
        for (int r = 0; r < 4; ++r) {
          float v = __expf(s4[g][m][r]);
          if (domask && (kb_m + r) > rowq) v = 0.f;
          p[r] = v;
          ls[g] += v;
        }
        pk[m].x = pkcvt(p[0], p[1]);
        pk[m].y = pkcvt(p[2], p[3]);
      }
      uint4 ua, ub;
      ua.x = pk[0].x; ua.y = pk[0].y; ua.z = pk[1].x; ua.w = pk[1].y;
      ub.x = pk[2].x; ub.y = pk[2].y; ub.z = pk[3].x; ub.w = pk[3].y;
      pa[g][0] = __builtin_bit_cast(bf16x8, ua);
      pa[g][1] = __builtin_bit_cast(bf16x8, ub);
    }
    // ---- PV (bv shared by both row-groups)
    __builtin_amdgcn_s_setprio(1);
    #pragma unroll
    for (int t = 0; t < 8; ++t) {
      const char* vl = (const char*)(Vc + (t * 16 + lr) * 64);
      bf16x8 bv0 = *(const bf16x8*)(vl + ((lk * 16) ^ vsw));
      bf16x8 bv1 = *(const bf16x8*)(vl + ((64 + lk * 16) ^ vsw));
      acc[0][t] = __builtin_amdgcn_mfma_f32_16x16x32_bf16(pa[0][0], bv0, acc[0][t], 0, 0, 0);
      acc[1][t] = __builtin_amdgcn_mfma_f32_16x16x32_bf16(pa[1][0], bv0, acc[1][t], 0, 0, 0);
      acc[0][t] = __builtin_amdgcn_mfma_f32_16x16x32_bf16(pa[0][1], bv1, acc[0][t], 0, 0, 0);
      acc[1][t] = __builtin_amdgcn_mfma_f32_16x16x32_bf16(pa[1][1], bv1, acc[1][t], 0, 0, 0);
    }
    __builtin_amdgcn_s_setprio(0);
  };

  {
    int wh;
    int kb0 = itemKb(0, wh);
    stage(0, kb0);
  }
  int cur = 0;
  #pragma unroll 1
  for (int j = 0; j < 17; ++j) {
    if (j + 1 < 17) {
      int wh;
      stage(cur ^ 1, itemKb(j + 1, wh));
      asm volatile("s_waitcnt vmcnt(8)" ::: "memory");
    } else {
      asm volatile("s_waitcnt vmcnt(0)" ::: "memory");
    }
    __builtin_amdgcn_sched_barrier(0);
    __builtin_amdgcn_s_barrier();
    int wh;
    const int kb = itemKb(j, wh);
    const unsigned short* Kc = (const unsigned short*)(gbase + cur * 16384);
    const unsigned short* Vc = (const unsigned short*)(gbase + 32768 + cur * 16384);
    if (wh == 0) computeTile(Kc, Vc, kb, qb0A, aqA, accA, lsA);
    else         computeTile(Kc, Vc, kb, qb0B, aqB, accB, lsB);
    __builtin_amdgcn_s_barrier();
    cur ^= 1;
  }

  // ---- combine A partials (G1 -> LDS -> G0), store
  float* comb  = (float*)ldsbuf;                 // [128][132] f32
  float* lcomb = (float*)(ldsbuf + 128 * 132 * 4);  // [128]
  if (grp == 1) {
    #pragma unroll
    for (int g = 0; g < 2; ++g) {
      #pragma unroll
      for (int t = 0; t < 8; ++t)
        #pragma unroll
        for (int r = 0; r < 4; ++r)
          comb[(w4 * 32 + g * 16 + lk * 4 + r) * 132 + t * 16 + lr] = accA[g][t][r];
      float v = lsA[g];
      v += __shfl_xor(v, 16);
      v += __shfl_xor(v, 32);
      if (lk == 0) lcomb[w4 * 32 + g * 16 + lr] = v;
    }
  }
  __syncthreads();
  if (grp == 0) {
    #pragma unroll
    for (int g = 0; g < 2; ++g) {
      float v = lsA[g];
      v += __shfl_xor(v, 16);
      v += __shfl_xor(v, 32);
      v += lcomb[w4 * 32 + g * 16 + lr];
      float rl[4];
      #pragma unroll
      for (int r = 0; r < 4; ++r) rl[r] = 1.0f / __shfl(v, lk * 4 + r);
      #pragma unroll
      for (int t = 0; t < 8; ++t) {
        #pragma unroll
        for (int r = 0; r < 4; ++r) {
          int srow = qb0A + w4 * 32 + g * 16 + lk * 4 + r;
          float o = (accA[g][t][r] +
                     comb[(w4 * 32 + g * 16 + lk * 4 + r) * 132 + t * 16 + lr]) * rl[r];
          attn_out[((size_t)(b * S) + srow) * 2048 + h * 128 + t * 16 + lr] = f2b(o);
        }
      }
    }
  } else {
    #pragma unroll
    for (int g = 0; g < 2; ++g) {
      float v = lsB[g];
      v += __shfl_xor(v, 16);
      v += __shfl_xor(v, 32);
      float rl[4];
      #pragma unroll
      for (int r = 0; r < 4; ++r) rl[r] = 1.0f / __shfl(v, lk * 4 + r);
      #pragma unroll
      for (int t = 0; t < 8; ++t) {
        #pragma unroll
        for (int r = 0; r < 4; ++r) {
          int srow = qb0B + w4 * 32 + g * 16 + lk * 4 + r;
          float o = accB[g][t][r] * rl[r];
          attn_out[((size_t)(b * S) + srow) * 2048 + h * 128 + t * 16 + lr] = f2b(o);
        }
      }
    }
  }
}

// ---------------- launch ----------------
extern "C" void kernel_launch(void* const* d_in, const int* in_sizes, int n_in,
                              void* d_out, int out_size, void* d_ws, size_t ws_size,
                              hipStream_t stream) {
  const float* x  = (const float*)d_in[0];
  const float* Wq = (const float*)d_in[1];
  const float* bq = (const float*)d_in[2];
  const float* Wk = (const float*)d_in[3];
  const float* bk = (const float*)d_in[4];
  const float* Wv = (const float*)d_in[5];
  const float* bv = (const float*)d_in[6];
  const float* Wo = (const float*)d_in[7];
  const float* bo = (const float*)d_in[8];

  const int B = 2, S = 2048, E = 2048, H = 16, D = 128;
  const int M = B * S;             // 4096
  const int Nqkv = H * D + 2 * D;  // 2304

  char* w = (char*)d_ws;
  unsigned short* xb    = (unsigned short*)w;                              // 16,777,216 B
  unsigned short* WqkvT = (unsigned short*)(w + 16777216);                 //  9,437,184 B
  unsigned short* qkv   = (unsigned short*)(w + 16777216 + 9437184);       // 18,874,368 B
  unsigned short* qr    = (unsigned short*)(w + 16777216 + 9437184 + 18874368); // 16,777,216 B
  unsigned short* kr    = qr + (size_t)B * H * S * D;
  unsigned short* vtb   = kr + (size_t)B * S * D;
  float*          cbias = (float*)(vtb + (size_t)B * S * D);
  unsigned short* WoT   = (unsigned short*)(cbias + 4096);
  unsigned short* attn_out = xb;     // alias: xb dead after gemm1

  k_cvt_bf16<<<dim3((M * E / 4) / 256), 256, 0, stream>>>(x, xb, M * E / 4);
  k_transpose<<<dim3(Nqkv / 32, E / 32, 2), 256, 0, stream>>>(Wq, Wk, Wv, Wo, WqkvT, WoT);
  k_bias_concat<<<dim3(9), 256, 0, stream>>>(bq, bk, bv, cbias);
  k_gemm_lds<1><<<dim3(Nqkv / 128, M / 128), 256, 0, stream>>>(xb, WqkvT, cbias, (void*)qkv, M, Nqkv, E);
  k_rope<<<dim3(B * S * (H + 1) / 4), 256, 0, stream>>>(qkv, qr, kr, S, H);
  k_vtrans<<<dim3(S / 32, D / 32, B), 256, 0, stream>>>(qkv, vtb, S);
  k_attn<<<dim3(S / 256, H, B), 512, 0, stream>>>(qr, kr, vtb, attn_out, S, H);
  k_gemm_lds<0><<<dim3(E / 128, M / 128), 256, 0, stream>>>(attn_out, WoT, bo, (void*)d_out, M, E, H * D);
}

// Round 13
// 214.890 us; speedup vs baseline: 1.1023x; 1.1023x over previous
//
#include <hip/hip_runtime.h>
#include <stdint.h>

typedef __bf16 bf16x8 __attribute__((ext_vector_type(8)));
typedef __bf16 bf16x2 __attribute__((ext_vector_type(2)));
typedef float  f32x4  __attribute__((ext_vector_type(4)));
typedef short  s16x8  __attribute__((ext_vector_type(8)));

__device__ inline unsigned short f2b(float f) {
  unsigned int u = __builtin_bit_cast(unsigned int, f);
  u += 0x7FFFu + ((u >> 16) & 1u);
  return (unsigned short)(u >> 16);
}
__device__ inline float b2f(unsigned short h) {
  unsigned int u = ((unsigned int)h) << 16;
  return __builtin_bit_cast(float, u);
}
// native pack: compiler emits v_cvt_pk_bf16_f32
__device__ inline unsigned int pkcvt(float a, float b) {
  bf16x2 t;
  t[0] = (__bf16)a;
  t[1] = (__bf16)b;
  return __builtin_bit_cast(unsigned int, t);
}
__device__ inline void gload_lds16(const void* g, void* l) {
  __builtin_amdgcn_global_load_lds(
      (const __attribute__((address_space(1))) unsigned int*)g,
      (__attribute__((address_space(3))) unsigned int*)l, 16, 0, 0);
}

// ---------------- elementwise f32 -> bf16 ----------------
__global__ void k_cvt_bf16(const float* __restrict__ in, unsigned short* __restrict__ out, int n4) {
  int i = blockIdx.x * blockDim.x + threadIdx.x;
  if (i < n4) {
    float4 v = ((const float4*)in)[i];
    ushort4 o;
    o.x = f2b(v.x); o.y = f2b(v.y); o.z = f2b(v.z); o.w = f2b(v.w);
    ((ushort4*)out)[i] = o;
  }
}

// ---------------- transpose f32 -> bf16 [N][K]; z=0: Wq|Wk|Wv concat, z=1: Wo ----------------
__global__ void k_transpose(const float* __restrict__ Wq, const float* __restrict__ Wk,
                            const float* __restrict__ Wv, const float* __restrict__ Wo,
                            unsigned short* __restrict__ dstQKV, unsigned short* __restrict__ dstO) {
  __shared__ float tile[32][33];
  int n0 = blockIdx.x * 32;
  int k0 = blockIdx.y * 32;
  const float* src; int ldn, noff, K;
  unsigned short* dst;
  if (blockIdx.z == 0) {
    K = 2048; dst = dstQKV;
    if (n0 < 2048)       { src = Wq; ldn = 2048; noff = n0; }
    else if (n0 < 2176)  { src = Wk; ldn = 128;  noff = n0 - 2048; }
    else                 { src = Wv; ldn = 128;  noff = n0 - 2176; }
  } else {
    if (n0 >= 2048) return;
    K = 2048; dst = dstO;
    src = Wo; ldn = 2048; noff = n0;
  }
  int tx = threadIdx.x & 31, ty = threadIdx.x >> 5;
  for (int yy = ty; yy < 32; yy += 8)
    tile[yy][tx] = src[(size_t)(k0 + yy) * ldn + noff + tx];
  __syncthreads();
  for (int yy = ty; yy < 32; yy += 8)
    dst[(size_t)(n0 + yy) * K + k0 + tx] = f2b(tile[tx][yy]);
}

// ---------------- bias concat [2304] ----------------
__global__ void k_bias_concat(const float* __restrict__ bq, const float* __restrict__ bk,
                              const float* __restrict__ bv, float* __restrict__ dst) {
  int i = blockIdx.x * 256 + threadIdx.x;
  if (i < 2304) dst[i] = (i < 2048) ? bq[i] : (i < 2176 ? bk[i - 2048] : bv[i - 2176]);
}

// ---------------- bf16 GEMM, 8-phase-style: C = A * Bt^T + bias ----------------
// BM=128, BN=256, BK=64, 8 waves (2Mx4N), per-wave 64x64 out, 3-buf LDS ring.
// Per K-tile: 4 phases {ds_read frag || issue G-loads || barrier; setprio; 8 MFMA;
// setprio; barrier}; vmcnt(6) once per K-tile (next tile's loads stay in flight).
// XOR swizzle byte^=(row&7)<<4 both sides (128B rows = T2's 16-way case).
template<int OUT_BF16>
__global__ __launch_bounds__(512)
void k_gemm8(const unsigned short* __restrict__ A, const unsigned short* __restrict__ Bt,
             const float* __restrict__ bias, void* __restrict__ Cout,
             int M, int N, int K) {
  __shared__ __align__(16) char smem[3][49152];  // per buf: A @0 (16KB), B @16KB (32KB)
  const int tid = threadIdx.x, lane = tid & 63, wid = tid >> 6;
  const int lr = lane & 15, lk = lane >> 4;
  const int wr = wid >> 2, wc = wid & 3;
  const int mb = blockIdx.y * 128, nb = blockIdx.x * 256;

  const char* Ab = (const char*)A;
  const char* Bb = (const char*)Bt;
  const int srow8 = lane >> 3;                                   // 0..7
  const int scolb = (((lane & 7) << 4) ^ ((srow8 & 7) << 4));    // pre-swizzled col byte
  const int fsw = (lr & 7) << 4;                                 // read-side XOR

  f32x4 acc[4][4];
  #pragma unroll
  for (int i = 0; i < 4; ++i)
    #pragma unroll
    for (int j = 0; j < 4; ++j) acc[i][j] = (f32x4){0.f, 0.f, 0.f, 0.f};

  auto stageA = [&](int buf, int kt) {
    #pragma unroll
    for (int r = 0; r < 2; ++r) {
      int row = r * 64 + wid * 8 + srow8;
      const char* src = Ab + ((size_t)(mb + row) * K + kt * 64) * 2 + scolb;
      gload_lds16(src, &smem[buf][r * 8192 + wid * 1024]);
    }
  };
  auto stageBr = [&](int buf, int kt, int r) {
    int row = r * 64 + wid * 8 + srow8;
    const char* src = Bb + ((size_t)(nb + row) * K + kt * 64) * 2 + scolb;
    gload_lds16(src, &smem[buf][16384 + r * 8192 + wid * 1024]);
  };

  const int ktn = K >> 6;
  stageA(0, 0);
  #pragma unroll
  for (int r = 0; r < 4; ++r) stageBr(0, 0, r);
  stageA(1, 1);
  #pragma unroll
  for (int r = 0; r < 4; ++r) stageBr(1, 1, r);

  int cur = 0;
  #pragma unroll 1
  for (int kt = 0; kt < ktn; ++kt) {
    const char* Ac = smem[cur];
    const char* Bc = smem[cur] + 16384;
    const bool pf = (kt + 2 < ktn);
    const int nbuf = (cur + 2 >= 3) ? cur - 1 : cur + 2;
    if (kt + 1 < ktn) asm volatile("s_waitcnt vmcnt(6)" ::: "memory");
    else              asm volatile("s_waitcnt vmcnt(0)" ::: "memory");
    __builtin_amdgcn_sched_barrier(0);
    __builtin_amdgcn_s_barrier();

    bf16x8 af[4][2];
    #pragma unroll
    for (int ph = 0; ph < 4; ++ph) {
      if (ph == 0) {
        #pragma unroll
        for (int m = 0; m < 4; ++m) {
          const char* ab = Ac + (wr * 64 + m * 16 + lr) * 128;
          af[m][0] = *(const bf16x8*)(ab + ((lk * 16) ^ fsw));
          af[m][1] = *(const bf16x8*)(ab + ((64 + lk * 16) ^ fsw));
        }
      }
      const char* bbp = Bc + (wc * 64 + ph * 16 + lr) * 128;
      bf16x8 bf0 = *(const bf16x8*)(bbp + ((lk * 16) ^ fsw));
      bf16x8 bf1 = *(const bf16x8*)(bbp + ((64 + lk * 16) ^ fsw));
      if (pf) {
        if (ph == 0) stageA(nbuf, kt + 2);
        else if (ph == 1) { stageBr(nbuf, kt + 2, 0); stageBr(nbuf, kt + 2, 1); }
        else if (ph == 2) stageBr(nbuf, kt + 2, 2);
        else              stageBr(nbuf, kt + 2, 3);
      }
      __builtin_amdgcn_s_barrier();
      __builtin_amdgcn_s_setprio(1);
      #pragma unroll
      for (int m = 0; m < 4; ++m) {
        acc[m][ph] = __builtin_amdgcn_mfma_f32_16x16x32_bf16(af[m][0], bf0, acc[m][ph], 0, 0, 0);
        acc[m][ph] = __builtin_amdgcn_mfma_f32_16x16x32_bf16(af[m][1], bf1, acc[m][ph], 0, 0, 0);
      }
      __builtin_amdgcn_s_setprio(0);
      __builtin_amdgcn_s_barrier();
    }
    cur = (cur + 1 == 3) ? 0 : cur + 1;
  }

  const int r0 = mb + wr * 64, c0 = nb + wc * 64;
  #pragma unroll
  for (int m = 0; m < 4; ++m) {
    #pragma unroll
    for (int n = 0; n < 4; ++n) {
      int col = c0 + n * 16 + lr;
      float bb = bias[col];
      #pragma unroll
      for (int rr = 0; rr < 4; ++rr) {
        int row = r0 + m * 16 + lk * 4 + rr;
        float v = acc[m][n][rr] + bb;
        if (OUT_BF16) ((unsigned short*)Cout)[(size_t)row * N + col] = f2b(v);
        else          ((float*)Cout)[(size_t)row * N + col] = v;
      }
    }
  }
}

// ---------------- RoPE (q heads + k); q pre-scaled by 1/sqrt(D) ----------------
__global__ void k_rope(const unsigned short* __restrict__ qkv,
                       unsigned short* __restrict__ qr,
                       unsigned short* __restrict__ kr,
                       int S, int H) {
  int R = blockIdx.x * 4 + (threadIdx.x >> 6);
  int lane = threadIdx.x & 63;
  int per_b = S * (H + 1);
  int b = R / per_b;
  int rem = R - b * per_b;
  int s = rem / (H + 1);
  int j = rem - s * (H + 1);
  const unsigned short* src = qkv + (size_t)(b * S + s) * 2304 + (j < H ? j * 128 : 2048);
  float x1 = b2f(src[lane]);
  float x2 = b2f(src[lane + 64]);
  float invf = expf(-(float)lane * (9.210340371976184f / 64.0f));
  float ang = (float)s * invf;
  float c = cosf(ang), sn = sinf(ang);
  float o1 = x1 * c - x2 * sn;
  float o2 = x1 * sn + x2 * c;
  unsigned short* dst;
  if (j < H) {
    const float scale = 0.08838834764831845f;  // fold 1/sqrt(128) into q
    o1 *= scale; o2 *= scale;
    dst = qr + ((size_t)(b * H + j) * S + s) * 128;
  } else {
    dst = kr + ((size_t)(b * S) + s) * 128;
  }
  dst[lane]      = f2b(o1);
  dst[lane + 64] = f2b(o2);
}

// ---------------- V transpose ----------------
__global__ void k_vtrans(const unsigned short* __restrict__ qkv,
                         unsigned short* __restrict__ vt, int S) {
  __shared__ unsigned short tile[32][33];
  int b = blockIdx.z;
  int s0 = blockIdx.x * 32, d0 = blockIdx.y * 32;
  int tx = threadIdx.x & 31, ty = threadIdx.x >> 5;
  for (int yy = ty; yy < 32; yy += 8)
    tile[yy][tx] = qkv[(size_t)(b * S + s0 + yy) * 2304 + 2176 + d0 + tx];
  __syncthreads();
  for (int yy = ty; yy < 32; yy += 8)
    vt[((size_t)b * 128 + d0 + yy) * S + s0 + tx] = tile[tx][yy];
}

// ---------------- causal flash attention (r7 verified: 68.3us) ----------------
// MQA, swapped QK^T, no-max softmax (q pre-scaled). K/V staged via
// global_load_lds w16, double-buffered, XOR-swizzled, counted vmcnt.
__global__ __launch_bounds__(256)
void k_attn(const unsigned short* __restrict__ qr,  // [B][H][S][128]
            const unsigned short* __restrict__ kr,  // [B][S][128]
            const unsigned short* __restrict__ vt,  // [B][128][S]
            unsigned short* __restrict__ attn_out,  // [B][S][2048]
            int S, int H) {
  const int b = blockIdx.z, h = blockIdx.y;
  const int tid = threadIdx.x, wid = tid >> 6, lane = tid & 63;
  const int lr = lane & 15, lk = lane >> 4;

  __shared__ unsigned short Kt[2][64 * 128];
  __shared__ unsigned short Vt[2][128 * 64];
  __shared__ unsigned short P_all[4][16][72];
  unsigned short (*P)[72] = P_all[wid];

  const char* kbyte = (const char*)(kr + (size_t)b * S * 128);
  const char* vbyte = (const char*)(vt + (size_t)b * 128 * S);
  const size_t vrow_bytes = (size_t)S * 2;

  const int krow0 = tid >> 4;
  const int kcb   = (tid & 15) << 4;
  const int vd0   = tid >> 3;
  const int vcb   = (tid & 7) << 4;
  const int lds_woff = (wid * 1024) >> 1;

  const int ksw = (lr & 7) << 4;

  const int ntiles = gridDim.x * 2;

  #pragma unroll 1
  for (int half = 0; half < 2; ++half) {
    const int qt  = (half == 0) ? blockIdx.x : (ntiles - 1 - blockIdx.x);
    const int qb0 = qt * 64;
    const int qw  = qb0 + wid * 16;

    const unsigned short* qptr = qr + ((size_t)(b * H + h) * S + (qw + lr)) * 128;
    bf16x8 aq[4];
    #pragma unroll
    for (int kk = 0; kk < 4; ++kk) aq[kk] = *(const bf16x8*)(qptr + kk * 32 + lk * 8);

    f32x4 accO[8];
    #pragma unroll
    for (int t = 0; t < 8; ++t) accO[t] = (f32x4){0.f, 0.f, 0.f, 0.f};
    float lsum = 0.f;

    auto stage = [&](int buf, int kb) {
      const char* kg = kbyte + (size_t)kb * 256;
      #pragma unroll
      for (int r = 0; r < 4; ++r) {
        int row = krow0 + r * 16;
        const char* src = kg + row * 256 + (kcb ^ ((row & 7) << 4));
        gload_lds16(src, (void*)(&Kt[buf][0] + lds_woff + r * 2048));
      }
      const char* vg = vbyte + (size_t)kb * 2;
      #pragma unroll
      for (int r = 0; r < 4; ++r) {
        int d = vd0 + r * 32;
        const char* src = vg + (size_t)d * vrow_bytes + (vcb ^ ((d & 7) << 4));
        gload_lds16(src, (void*)(&Vt[buf][0] + lds_woff + r * 2048));
      }
    };

    int cur = 0;
    stage(0, 0);

    #pragma unroll 1
    for (int kb = 0; kb <= qb0; kb += 64) {
      if (kb + 64 <= qb0) {
        stage(cur ^ 1, kb + 64);
        asm volatile("s_waitcnt vmcnt(8)" ::: "memory");   // drain current tile only
      } else {
        asm volatile("s_waitcnt vmcnt(0)" ::: "memory");
      }
      __builtin_amdgcn_sched_barrier(0);
      __builtin_amdgcn_s_barrier();        // tile data visible
      const bool diag = (kb == qb0);
      const unsigned short* Kc = &Kt[cur][0];
      const unsigned short* Vc = &Vt[cur][0];

      // ---- QK^T (swapped)
      bf16x8 kf[4][4];
      #pragma unroll
      for (int m = 0; m < 4; ++m) {
        const char* kl = (const char*)(Kc + (m * 16 + lr) * 128);
        #pragma unroll
        for (int kk = 0; kk < 4; ++kk)
          kf[m][kk] = *(const bf16x8*)(kl + ((kk * 64 + lk * 16) ^ ksw));
      }
      f32x4 s4[4];
      #pragma unroll
      for (int m = 0; m < 4; ++m) s4[m] = (f32x4){0.f, 0.f, 0.f, 0.f};
      __builtin_amdgcn_s_setprio(1);
      #pragma unroll
      for (int kk = 0; kk < 4; ++kk)
        #pragma unroll
        for (int m = 0; m < 4; ++m)
          s4[m] = __builtin_amdgcn_mfma_f32_16x16x32_bf16(kf[m][kk], aq[kk], s4[m], 0, 0, 0);
      __builtin_amdgcn_s_setprio(0);

      // ---- exp, diag mask, per-lane denominator
      #pragma unroll
      for (int m = 0; m < 4; ++m) {
        float p[4];
        #pragma unroll
        for (int r = 0; r < 4; ++r) {
          float v = __expf(s4[m][r]);
          if (diag && (m * 16 + lk * 4 + r) > (wid * 16 + lr)) v = 0.f;
          p[r] = v;
          lsum += v;
        }
        uint2 w;
        w.x = pkcvt(p[0], p[1]);
        w.y = pkcvt(p[2], p[3]);
        *(uint2*)&P[lr][m * 16 + lk * 4] = w;
      }

      // ---- PV from staged V
      #pragma unroll
      for (int ks = 0; ks < 2; ++ks) {
        bf16x8 pa = *(const bf16x8*)&P[lr][ks * 32 + lk * 8];
        __builtin_amdgcn_s_setprio(1);
        #pragma unroll
        for (int t = 0; t < 8; ++t) {
          const char* vl = (const char*)(Vc + (t * 16 + lr) * 64);
          bf16x8 bv = *(const bf16x8*)(vl + ((ks * 64 + lk * 16) ^ ksw));
          accO[t] = __builtin_amdgcn_mfma_f32_16x16x32_bf16(pa, bv, accO[t], 0, 0, 0);
        }
        __builtin_amdgcn_s_setprio(0);
      }
      __builtin_amdgcn_s_barrier();        // all reads of cur done
      cur ^= 1;
    }

    // ---- epilogue
    lsum += __shfl_xor(lsum, 16);
    lsum += __shfl_xor(lsum, 32);
    float rl[4];
    #pragma unroll
    for (int r = 0; r < 4; ++r) rl[r] = 1.0f / __shfl(lsum, lk * 4 + r);
    #pragma unroll
    for (int t = 0; t < 8; ++t) {
      #pragma unroll
      for (int r = 0; r < 4; ++r) {
        int srow = qw + lk * 4 + r;
        float o = accO[t][r] * rl[r];
        attn_out[((size_t)(b * S) + srow) * 2048 + h * 128 + t * 16 + lr] = f2b(o);
      }
    }
  }
}

// ---------------- launch ----------------
extern "C" void kernel_launch(void* const* d_in, const int* in_sizes, int n_in,
                              void* d_out, int out_size, void* d_ws, size_t ws_size,
                              hipStream_t stream) {
  const float* x  = (const float*)d_in[0];
  const float* Wq = (const float*)d_in[1];
  const float* bq = (const float*)d_in[2];
  const float* Wk = (const float*)d_in[3];
  const float* bk = (const float*)d_in[4];
  const float* Wv = (const float*)d_in[5];
  const float* bv = (const float*)d_in[6];
  const float* Wo = (const float*)d_in[7];
  const float* bo = (const float*)d_in[8];

  const int B = 2, S = 2048, E = 2048, H = 16, D = 128;
  const int M = B * S;             // 4096
  const int Nqkv = H * D + 2 * D;  // 2304

  char* w = (char*)d_ws;
  unsigned short* xb    = (unsigned short*)w;                              // 16,777,216 B
  unsigned short* WqkvT = (unsigned short*)(w + 16777216);                 //  9,437,184 B
  unsigned short* qkv   = (unsigned short*)(w + 16777216 + 9437184);       // 18,874,368 B
  unsigned short* qr    = (unsigned short*)(w + 16777216 + 9437184 + 18874368); // 16,777,216 B
  unsigned short* kr    = qr + (size_t)B * H * S * D;
  unsigned short* vtb   = kr + (size_t)B * S * D;
  float*          cbias = (float*)(vtb + (size_t)B * S * D);
  unsigned short* WoT   = (unsigned short*)(cbias + 4096);
  unsigned short* attn_out = xb;     // alias: xb dead after gemm1

  k_cvt_bf16<<<dim3((M * E / 4) / 256), 256, 0, stream>>>(x, xb, M * E / 4);
  k_transpose<<<dim3(Nqkv / 32, E / 32, 2), 256, 0, stream>>>(Wq, Wk, Wv, Wo, WqkvT, WoT);
  k_bias_concat<<<dim3(9), 256, 0, stream>>>(bq, bk, bv, cbias);
  k_gemm8<1><<<dim3(Nqkv / 256, M / 128), 512, 0, stream>>>(xb, WqkvT, cbias, (void*)qkv, M, Nqkv, E);
  k_rope<<<dim3(B * S * (H + 1) / 4), 256, 0, stream>>>(qkv, qr, kr, S, H);
  k_vtrans<<<dim3(S / 32, D / 32, B), 256, 0, stream>>>(qkv, vtb, S);
  k_attn<<<dim3(S / 128, H, B), 256, 0, stream>>>(qr, kr, vtb, attn_out, S, H);
  k_gemm8<0><<<dim3(E / 256, M / 128), 512, 0, stream>>>(attn_out, WoT, bo, (void*)d_out, M, E, H * D);
}

// Round 14
// 204.261 us; speedup vs baseline: 1.1597x; 1.0520x over previous
//
#include <hip/hip_runtime.h>
#include <stdint.h>

typedef __bf16 bf16x8 __attribute__((ext_vector_type(8)));
typedef __bf16 bf16x2 __attribute__((ext_vector_type(2)));
typedef float  f32x4  __attribute__((ext_vector_type(4)));
typedef short  s16x8  __attribute__((ext_vector_type(8)));

__device__ inline unsigned short f2b(float f) {
  unsigned int u = __builtin_bit_cast(unsigned int, f);
  u += 0x7FFFu + ((u >> 16) & 1u);
  return (unsigned short)(u >> 16);
}
__device__ inline float b2f(unsigned short h) {
  unsigned int u = ((unsigned int)h) << 16;
  return __builtin_bit_cast(float, u);
}
// native pack: compiler emits v_cvt_pk_bf16_f32
__device__ inline unsigned int pkcvt(float a, float b) {
  bf16x2 t;
  t[0] = (__bf16)a;
  t[1] = (__bf16)b;
  return __builtin_bit_cast(unsigned int, t);
}
__device__ inline void gload_lds16(const void* g, void* l) {
  __builtin_amdgcn_global_load_lds(
      (const __attribute__((address_space(1))) unsigned int*)g,
      (__attribute__((address_space(3))) unsigned int*)l, 16, 0, 0);
}

// ---------------- elementwise f32 -> bf16 ----------------
__global__ void k_cvt_bf16(const float* __restrict__ in, unsigned short* __restrict__ out, int n4) {
  int i = blockIdx.x * blockDim.x + threadIdx.x;
  if (i < n4) {
    float4 v = ((const float4*)in)[i];
    ushort4 o;
    o.x = f2b(v.x); o.y = f2b(v.y); o.z = f2b(v.z); o.w = f2b(v.w);
    ((ushort4*)out)[i] = o;
  }
}

// ---------------- transpose f32 -> bf16 [N][K]; z=0: Wq|Wk|Wv concat, z=1: Wo ----------------
__global__ void k_transpose(const float* __restrict__ Wq, const float* __restrict__ Wk,
                            const float* __restrict__ Wv, const float* __restrict__ Wo,
                            unsigned short* __restrict__ dstQKV, unsigned short* __restrict__ dstO) {
  __shared__ float tile[32][33];
  int n0 = blockIdx.x * 32;
  int k0 = blockIdx.y * 32;
  const float* src; int ldn, noff, K;
  unsigned short* dst;
  if (blockIdx.z == 0) {
    K = 2048; dst = dstQKV;
    if (n0 < 2048)       { src = Wq; ldn = 2048; noff = n0; }
    else if (n0 < 2176)  { src = Wk; ldn = 128;  noff = n0 - 2048; }
    else                 { src = Wv; ldn = 128;  noff = n0 - 2176; }
  } else {
    if (n0 >= 2048) return;
    K = 2048; dst = dstO;
    src = Wo; ldn = 2048; noff = n0;
  }
  int tx = threadIdx.x & 31, ty = threadIdx.x >> 5;
  for (int yy = ty; yy < 32; yy += 8)
    tile[yy][tx] = src[(size_t)(k0 + yy) * ldn + noff + tx];
  __syncthreads();
  for (int yy = ty; yy < 32; yy += 8)
    dst[(size_t)(n0 + yy) * K + k0 + tx] = f2b(tile[tx][yy]);
}

// ---------------- bf16 GEMM: C = A * Bt^T + bias (r10 verified + XCD swizzle) ----------------
// 128x128 tile, BK=32, global_load_lds w16, 3-buffer ring, 2-deep prefetch,
// counted vmcnt. XCD-aware block swizzle (grids are %8==0 -> simple bijective).
// BIAS3: col-selected bias from (b0|b1|b2) at boundaries 2048/2176 (QKV path).
template<int OUT_BF16, int BIAS3>
__global__ __launch_bounds__(256)
void k_gemm_lds(const unsigned short* __restrict__ A, const unsigned short* __restrict__ Bt,
                const float* __restrict__ b0, const float* __restrict__ b1,
                const float* __restrict__ b2, void* __restrict__ Cout,
                int M, int N, int K) {
  __shared__ unsigned short As[3][4096];   // [buf][128*32] linear
  __shared__ unsigned short Bs[3][4096];
  const int tid  = threadIdx.x;
  const int lane = tid & 63, wid = tid >> 6;
  const int lr = lane & 15, lk = lane >> 4;
  const int wr = wid >> 1,  wc = wid & 1;

  // XCD-aware swizzle: same-XCD blocks get a contiguous tile range
  const int nwg = gridDim.x * gridDim.y;
  const int flat = blockIdx.y * gridDim.x + blockIdx.x;
  const int swz = (flat & 7) * (nwg >> 3) + (flat >> 3);
  const int mb = (swz / gridDim.x) * 128;
  const int nb = (swz % gridDim.x) * 128;

  const int srow = tid >> 2, scb = (tid & 3) * 8;
  const size_t gA = (size_t)(mb + srow) * K + scb;
  const size_t gB = (size_t)(nb + srow) * K + scb;
  const int ldso = wid * 512;

  f32x4 acc[4][4];
  #pragma unroll
  for (int i = 0; i < 4; ++i)
    #pragma unroll
    for (int j = 0; j < 4; ++j) acc[i][j] = (f32x4){0.f, 0.f, 0.f, 0.f};

  auto stage = [&](int buf, int kt) {
    const size_t ko = (size_t)kt * 32;
    gload_lds16(A  + gA + ko,                  &As[buf][ldso]);
    gload_lds16(A  + gA + 64 * (size_t)K + ko, &As[buf][2048 + ldso]);
    gload_lds16(Bt + gB + ko,                  &Bs[buf][ldso]);
    gload_lds16(Bt + gB + 64 * (size_t)K + ko, &Bs[buf][2048 + ldso]);
  };

  const int ktn = K >> 5;
  stage(0, 0);
  stage(1, 1);

  int cur = 0;
  #pragma unroll 1
  for (int kt = 0; kt < ktn; ++kt) {
    if (kt + 2 < ktn) {
      int nbuf = cur + 2; if (nbuf >= 3) nbuf -= 3;
      stage(nbuf, kt + 2);
      asm volatile("s_waitcnt vmcnt(8)" ::: "memory");   // tile kt done; kt+1,kt+2 in flight
    } else if (kt + 1 < ktn) {
      asm volatile("s_waitcnt vmcnt(4)" ::: "memory");
    } else {
      asm volatile("s_waitcnt vmcnt(0)" ::: "memory");
    }
    __builtin_amdgcn_sched_barrier(0);
    __builtin_amdgcn_s_barrier();
    bf16x8 af[4], bfv[4];
    #pragma unroll
    for (int m = 0; m < 4; ++m)
      af[m]  = *(const bf16x8*)&As[cur][(wr * 64 + m * 16 + lr) * 32 + lk * 8];
    #pragma unroll
    for (int n = 0; n < 4; ++n)
      bfv[n] = *(const bf16x8*)&Bs[cur][(wc * 64 + n * 16 + lr) * 32 + lk * 8];
    #pragma unroll
    for (int m = 0; m < 4; ++m)
      #pragma unroll
      for (int n = 0; n < 4; ++n)
        acc[m][n] = __builtin_amdgcn_mfma_f32_16x16x32_bf16(af[m], bfv[n], acc[m][n], 0, 0, 0);
    __builtin_amdgcn_s_barrier();
    ++cur; if (cur == 3) cur = 0;
  }

  const int r0 = mb + wr * 64, c0 = nb + wc * 64;
  #pragma unroll
  for (int m = 0; m < 4; ++m) {
    #pragma unroll
    for (int n = 0; n < 4; ++n) {
      int col = c0 + n * 16 + lr;
      float bb;
      if (BIAS3) bb = (col < 2048) ? b0[col] : (col < 2176 ? b1[col - 2048] : b2[col - 2176]);
      else       bb = b0[col];
      #pragma unroll
      for (int r = 0; r < 4; ++r) {
        int row = r0 + m * 16 + lk * 4 + r;
        float v = acc[m][n][r] + bb;
        if (OUT_BF16) ((unsigned short*)Cout)[(size_t)row * N + col] = f2b(v);
        else          ((float*)Cout)[(size_t)row * N + col] = v;
      }
    }
  }
}

// ---------------- RoPE (q heads + k); q pre-scaled by 1/sqrt(D) ----------------
__global__ void k_rope(const unsigned short* __restrict__ qkv,
                       unsigned short* __restrict__ qr,
                       unsigned short* __restrict__ kr,
                       int S, int H) {
  int R = blockIdx.x * 4 + (threadIdx.x >> 6);
  int lane = threadIdx.x & 63;
  int per_b = S * (H + 1);
  int b = R / per_b;
  int rem = R - b * per_b;
  int s = rem / (H + 1);
  int j = rem - s * (H + 1);
  const unsigned short* src = qkv + (size_t)(b * S + s) * 2304 + (j < H ? j * 128 : 2048);
  float x1 = b2f(src[lane]);
  float x2 = b2f(src[lane + 64]);
  float invf = expf(-(float)lane * (9.210340371976184f / 64.0f));
  float ang = (float)s * invf;
  float c = cosf(ang), sn = sinf(ang);
  float o1 = x1 * c - x2 * sn;
  float o2 = x1 * sn + x2 * c;
  unsigned short* dst;
  if (j < H) {
    const float scale = 0.08838834764831845f;  // fold 1/sqrt(128) into q
    o1 *= scale; o2 *= scale;
    dst = qr + ((size_t)(b * H + j) * S + s) * 128;
  } else {
    dst = kr + ((size_t)(b * S) + s) * 128;
  }
  dst[lane]      = f2b(o1);
  dst[lane + 64] = f2b(o2);
}

// ---------------- V transpose ----------------
__global__ void k_vtrans(const unsigned short* __restrict__ qkv,
                         unsigned short* __restrict__ vt, int S) {
  __shared__ unsigned short tile[32][33];
  int b = blockIdx.z;
  int s0 = blockIdx.x * 32, d0 = blockIdx.y * 32;
  int tx = threadIdx.x & 31, ty = threadIdx.x >> 5;
  for (int yy = ty; yy < 32; yy += 8)
    tile[yy][tx] = qkv[(size_t)(b * S + s0 + yy) * 2304 + 2176 + d0 + tx];
  __syncthreads();
  for (int yy = ty; yy < 32; yy += 8)
    vt[((size_t)b * 128 + d0 + yy) * S + s0 + tx] = tile[tx][yy];
}

// ---------------- causal flash attention (r7 verified: 68.3us) ----------------
// MQA, swapped QK^T, no-max softmax (q pre-scaled). K/V staged via
// global_load_lds w16, double-buffered, XOR-swizzled, counted vmcnt.
__global__ __launch_bounds__(256)
void k_attn(const unsigned short* __restrict__ qr,  // [B][H][S][128]
            const unsigned short* __restrict__ kr,  // [B][S][128]
            const unsigned short* __restrict__ vt,  // [B][128][S]
            unsigned short* __restrict__ attn_out,  // [B][S][2048]
            int S, int H) {
  const int b = blockIdx.z, h = blockIdx.y;
  const int tid = threadIdx.x, wid = tid >> 6, lane = tid & 63;
  const int lr = lane & 15, lk = lane >> 4;

  __shared__ unsigned short Kt[2][64 * 128];
  __shared__ unsigned short Vt[2][128 * 64];
  __shared__ unsigned short P_all[4][16][72];
  unsigned short (*P)[72] = P_all[wid];

  const char* kbyte = (const char*)(kr + (size_t)b * S * 128);
  const char* vbyte = (const char*)(vt + (size_t)b * 128 * S);
  const size_t vrow_bytes = (size_t)S * 2;

  const int krow0 = tid >> 4;
  const int kcb   = (tid & 15) << 4;
  const int vd0   = tid >> 3;
  const int vcb   = (tid & 7) << 4;
  const int lds_woff = (wid * 1024) >> 1;

  const int ksw = (lr & 7) << 4;

  const int ntiles = gridDim.x * 2;

  #pragma unroll 1
  for (int half = 0; half < 2; ++half) {
    const int qt  = (half == 0) ? blockIdx.x : (ntiles - 1 - blockIdx.x);
    const int qb0 = qt * 64;
    const int qw  = qb0 + wid * 16;

    const unsigned short* qptr = qr + ((size_t)(b * H + h) * S + (qw + lr)) * 128;
    bf16x8 aq[4];
    #pragma unroll
    for (int kk = 0; kk < 4; ++kk) aq[kk] = *(const bf16x8*)(qptr + kk * 32 + lk * 8);

    f32x4 accO[8];
    #pragma unroll
    for (int t = 0; t < 8; ++t) accO[t] = (f32x4){0.f, 0.f, 0.f, 0.f};
    float lsum = 0.f;

    auto stage = [&](int buf, int kb) {
      const char* kg = kbyte + (size_t)kb * 256;
      #pragma unroll
      for (int r = 0; r < 4; ++r) {
        int row = krow0 + r * 16;
        const char* src = kg + row * 256 + (kcb ^ ((row & 7) << 4));
        gload_lds16(src, (void*)(&Kt[buf][0] + lds_woff + r * 2048));
      }
      const char* vg = vbyte + (size_t)kb * 2;
      #pragma unroll
      for (int r = 0; r < 4; ++r) {
        int d = vd0 + r * 32;
        const char* src = vg + (size_t)d * vrow_bytes + (vcb ^ ((d & 7) << 4));
        gload_lds16(src, (void*)(&Vt[buf][0] + lds_woff + r * 2048));
      }
    };

    int cur = 0;
    stage(0, 0);

    #pragma unroll 1
    for (int kb = 0; kb <= qb0; kb += 64) {
      if (kb + 64 <= qb0) {
        stage(cur ^ 1, kb + 64);
        asm volatile("s_waitcnt vmcnt(8)" ::: "memory");   // drain current tile only
      } else {
        asm volatile("s_waitcnt vmcnt(0)" ::: "memory");
      }
      __builtin_amdgcn_sched_barrier(0);
      __builtin_amdgcn_s_barrier();        // tile data visible
      const bool diag = (kb == qb0);
      const unsigned short* Kc = &Kt[cur][0];
      const unsigned short* Vc = &Vt[cur][0];

      // ---- QK^T (swapped)
      bf16x8 kf[4][4];
      #pragma unroll
      for (int m = 0; m < 4; ++m) {
        const char* kl = (const char*)(Kc + (m * 16 + lr) * 128);
        #pragma unroll
        for (int kk = 0; kk < 4; ++kk)
          kf[m][kk] = *(const bf16x8*)(kl + ((kk * 64 + lk * 16) ^ ksw));
      }
      f32x4 s4[4];
      #pragma unroll
      for (int m = 0; m < 4; ++m) s4[m] = (f32x4){0.f, 0.f, 0.f, 0.f};
      __builtin_amdgcn_s_setprio(1);
      #pragma unroll
      for (int kk = 0; kk < 4; ++kk)
        #pragma unroll
        for (int m = 0; m < 4; ++m)
          s4[m] = __builtin_amdgcn_mfma_f32_16x16x32_bf16(kf[m][kk], aq[kk], s4[m], 0, 0, 0);
      __builtin_amdgcn_s_setprio(0);

      // ---- exp, diag mask, per-lane denominator
      #pragma unroll
      for (int m = 0; m < 4; ++m) {
        float p[4];
        #pragma unroll
        for (int r = 0; r < 4; ++r) {
          float v = __expf(s4[m][r]);
          if (diag && (m * 16 + lk * 4 + r) > (wid * 16 + lr)) v = 0.f;
          p[r] = v;
          lsum += v;
        }
        uint2 w;
        w.x = pkcvt(p[0], p[1]);
        w.y = pkcvt(p[2], p[3]);
        *(uint2*)&P[lr][m * 16 + lk * 4] = w;
      }

      // ---- PV from staged V
      #pragma unroll
      for (int ks = 0; ks < 2; ++ks) {
        bf16x8 pa = *(const bf16x8*)&P[lr][ks * 32 + lk * 8];
        __builtin_amdgcn_s_setprio(1);
        #pragma unroll
        for (int t = 0; t < 8; ++t) {
          const char* vl = (const char*)(Vc + (t * 16 + lr) * 64);
          bf16x8 bv = *(const bf16x8*)(vl + ((ks * 64 + lk * 16) ^ ksw));
          accO[t] = __builtin_amdgcn_mfma_f32_16x16x32_bf16(pa, bv, accO[t], 0, 0, 0);
        }
        __builtin_amdgcn_s_setprio(0);
      }
      __builtin_amdgcn_s_barrier();        // all reads of cur done
      cur ^= 1;
    }

    // ---- epilogue
    lsum += __shfl_xor(lsum, 16);
    lsum += __shfl_xor(lsum, 32);
    float rl[4];
    #pragma unroll
    for (int r = 0; r < 4; ++r) rl[r] = 1.0f / __shfl(lsum, lk * 4 + r);
    #pragma unroll
    for (int t = 0; t < 8; ++t) {
      #pragma unroll
      for (int r = 0; r < 4; ++r) {
        int srow = qw + lk * 4 + r;
        float o = accO[t][r] * rl[r];
        attn_out[((size_t)(b * S) + srow) * 2048 + h * 128 + t * 16 + lr] = f2b(o);
      }
    }
  }
}

// ---------------- launch ----------------
extern "C" void kernel_launch(void* const* d_in, const int* in_sizes, int n_in,
                              void* d_out, int out_size, void* d_ws, size_t ws_size,
                              hipStream_t stream) {
  const float* x  = (const float*)d_in[0];
  const float* Wq = (const float*)d_in[1];
  const float* bq = (const float*)d_in[2];
  const float* Wk = (const float*)d_in[3];
  const float* bk = (const float*)d_in[4];
  const float* Wv = (const float*)d_in[5];
  const float* bv = (const float*)d_in[6];
  const float* Wo = (const float*)d_in[7];
  const float* bo = (const float*)d_in[8];

  const int B = 2, S = 2048, E = 2048, H = 16, D = 128;
  const int M = B * S;             // 4096
  const int Nqkv = H * D + 2 * D;  // 2304

  char* w = (char*)d_ws;
  unsigned short* xb    = (unsigned short*)w;                              // 16,777,216 B
  unsigned short* WqkvT = (unsigned short*)(w + 16777216);                 //  9,437,184 B
  unsigned short* qkv   = (unsigned short*)(w + 16777216 + 9437184);       // 18,874,368 B
  unsigned short* qr    = (unsigned short*)(w + 16777216 + 9437184 + 18874368); // 16,777,216 B
  unsigned short* kr    = qr + (size_t)B * H * S * D;
  unsigned short* vtb   = kr + (size_t)B * S * D;
  float*          cbias = (float*)(vtb + (size_t)B * S * D);   // unused (kept for layout)
  unsigned short* WoT   = (unsigned short*)(cbias + 4096);
  unsigned short* attn_out = xb;     // alias: xb dead after gemm1

  k_cvt_bf16<<<dim3((M * E / 4) / 256), 256, 0, stream>>>(x, xb, M * E / 4);
  k_transpose<<<dim3(Nqkv / 32, E / 32, 2), 256, 0, stream>>>(Wq, Wk, Wv, Wo, WqkvT, WoT);
  k_gemm_lds<1, 1><<<dim3(Nqkv / 128, M / 128), 256, 0, stream>>>(xb, WqkvT, bq, bk, bv, (void*)qkv, M, Nqkv, E);
  k_rope<<<dim3(B * S * (H + 1) / 4), 256, 0, stream>>>(qkv, qr, kr, S, H);
  k_vtrans<<<dim3(S / 32, D / 32, B), 256, 0, stream>>>(qkv, vtb, S);
  k_attn<<<dim3(S / 128, H, B), 256, 0, stream>>>(qr, kr, vtb, attn_out, S, H);
  k_gemm_lds<0, 0><<<dim3(E / 128, M / 128), 256, 0, stream>>>(attn_out, WoT, bo, nullptr, nullptr, (void*)d_out, M, E, H * D);
}

// Round 15
// 196.422 us; speedup vs baseline: 1.2060x; 1.0399x over previous
//
#include <hip/hip_runtime.h>
#include <stdint.h>

typedef __bf16 bf16x8 __attribute__((ext_vector_type(8)));
typedef __bf16 bf16x2 __attribute__((ext_vector_type(2)));
typedef float  f32x4  __attribute__((ext_vector_type(4)));
typedef short  s16x8  __attribute__((ext_vector_type(8)));

__device__ inline unsigned short f2b(float f) {
  unsigned int u = __builtin_bit_cast(unsigned int, f);
  u += 0x7FFFu + ((u >> 16) & 1u);
  return (unsigned short)(u >> 16);
}
__device__ inline float b2f(unsigned short h) {
  unsigned int u = ((unsigned int)h) << 16;
  return __builtin_bit_cast(float, u);
}
__device__ inline unsigned int pkcvt(float a, float b) {
  bf16x2 t;
  t[0] = (__bf16)a;
  t[1] = (__bf16)b;
  return __builtin_bit_cast(unsigned int, t);
}
__device__ inline void gload_lds16(const void* g, void* l) {
  __builtin_amdgcn_global_load_lds(
      (const __attribute__((address_space(1))) unsigned int*)g,
      (__attribute__((address_space(3))) unsigned int*)l, 16, 0, 0);
}

// ---------------- elementwise f32 -> bf16 ----------------
__global__ void k_cvt_bf16(const float* __restrict__ in, unsigned short* __restrict__ out, int n4) {
  int i = blockIdx.x * blockDim.x + threadIdx.x;
  if (i < n4) {
    float4 v = ((const float4*)in)[i];
    ushort4 o;
    o.x = f2b(v.x); o.y = f2b(v.y); o.z = f2b(v.z); o.w = f2b(v.w);
    ((ushort4*)out)[i] = o;
  }
}

// ---------------- transpose f32 -> bf16 [N][K]; z=0: Wq|Wk|Wv concat, z=1: Wo ----------------
__global__ void k_transpose(const float* __restrict__ Wq, const float* __restrict__ Wk,
                            const float* __restrict__ Wv, const float* __restrict__ Wo,
                            unsigned short* __restrict__ dstQKV, unsigned short* __restrict__ dstO) {
  __shared__ float tile[32][33];
  int n0 = blockIdx.x * 32;
  int k0 = blockIdx.y * 32;
  const float* src; int ldn, noff, K;
  unsigned short* dst;
  if (blockIdx.z == 0) {
    K = 2048; dst = dstQKV;
    if (n0 < 2048)       { src = Wq; ldn = 2048; noff = n0; }
    else if (n0 < 2176)  { src = Wk; ldn = 128;  noff = n0 - 2048; }
    else                 { src = Wv; ldn = 128;  noff = n0 - 2176; }
  } else {
    if (n0 >= 2048) return;
    K = 2048; dst = dstO;
    src = Wo; ldn = 2048; noff = n0;
  }
  int tx = threadIdx.x & 31, ty = threadIdx.x >> 5;
  for (int yy = ty; yy < 32; yy += 8)
    tile[yy][tx] = src[(size_t)(k0 + yy) * ldn + noff + tx];
  __syncthreads();
  for (int yy = ty; yy < 32; yy += 8)
    dst[(size_t)(n0 + yy) * K + k0 + tx] = f2b(tile[tx][yy]);
}

// ---------------- bf16 GEMM: C = A * Bt^T + bias (r14 verified) ----------------
template<int OUT_BF16, int BIAS3>
__global__ __launch_bounds__(256)
void k_gemm_lds(const unsigned short* __restrict__ A, const unsigned short* __restrict__ Bt,
                const float* __restrict__ b0, const float* __restrict__ b1,
                const float* __restrict__ b2, void* __restrict__ Cout,
                int M, int N, int K) {
  __shared__ unsigned short As[3][4096];
  __shared__ unsigned short Bs[3][4096];
  const int tid  = threadIdx.x;
  const int lane = tid & 63, wid = tid >> 6;
  const int lr = lane & 15, lk = lane >> 4;
  const int wr = wid >> 1,  wc = wid & 1;

  const int nwg = gridDim.x * gridDim.y;
  const int flat = blockIdx.y * gridDim.x + blockIdx.x;
  const int swz = (flat & 7) * (nwg >> 3) + (flat >> 3);
  const int mb = (swz / gridDim.x) * 128;
  const int nb = (swz % gridDim.x) * 128;

  const int srow = tid >> 2, scb = (tid & 3) * 8;
  const size_t gA = (size_t)(mb + srow) * K + scb;
  const size_t gB = (size_t)(nb + srow) * K + scb;
  const int ldso = wid * 512;

  f32x4 acc[4][4];
  #pragma unroll
  for (int i = 0; i < 4; ++i)
    #pragma unroll
    for (int j = 0; j < 4; ++j) acc[i][j] = (f32x4){0.f, 0.f, 0.f, 0.f};

  auto stage = [&](int buf, int kt) {
    const size_t ko = (size_t)kt * 32;
    gload_lds16(A  + gA + ko,                  &As[buf][ldso]);
    gload_lds16(A  + gA + 64 * (size_t)K + ko, &As[buf][2048 + ldso]);
    gload_lds16(Bt + gB + ko,                  &Bs[buf][ldso]);
    gload_lds16(Bt + gB + 64 * (size_t)K + ko, &Bs[buf][2048 + ldso]);
  };

  const int ktn = K >> 5;
  stage(0, 0);
  stage(1, 1);

  int cur = 0;
  #pragma unroll 1
  for (int kt = 0; kt < ktn; ++kt) {
    if (kt + 2 < ktn) {
      int nbuf = cur + 2; if (nbuf >= 3) nbuf -= 3;
      stage(nbuf, kt + 2);
      asm volatile("s_waitcnt vmcnt(8)" ::: "memory");
    } else if (kt + 1 < ktn) {
      asm volatile("s_waitcnt vmcnt(4)" ::: "memory");
    } else {
      asm volatile("s_waitcnt vmcnt(0)" ::: "memory");
    }
    __builtin_amdgcn_sched_barrier(0);
    __builtin_amdgcn_s_barrier();
    bf16x8 af[4], bfv[4];
    #pragma unroll
    for (int m = 0; m < 4; ++m)
      af[m]  = *(const bf16x8*)&As[cur][(wr * 64 + m * 16 + lr) * 32 + lk * 8];
    #pragma unroll
    for (int n = 0; n < 4; ++n)
      bfv[n] = *(const bf16x8*)&Bs[cur][(wc * 64 + n * 16 + lr) * 32 + lk * 8];
    #pragma unroll
    for (int m = 0; m < 4; ++m)
      #pragma unroll
      for (int n = 0; n < 4; ++n)
        acc[m][n] = __builtin_amdgcn_mfma_f32_16x16x32_bf16(af[m], bfv[n], acc[m][n], 0, 0, 0);
    __builtin_amdgcn_s_barrier();
    ++cur; if (cur == 3) cur = 0;
  }

  const int r0 = mb + wr * 64, c0 = nb + wc * 64;
  #pragma unroll
  for (int m = 0; m < 4; ++m) {
    #pragma unroll
    for (int n = 0; n < 4; ++n) {
      int col = c0 + n * 16 + lr;
      float bb;
      if (BIAS3) bb = (col < 2048) ? b0[col] : (col < 2176 ? b1[col - 2048] : b2[col - 2176]);
      else       bb = b0[col];
      #pragma unroll
      for (int r = 0; r < 4; ++r) {
        int row = r0 + m * 16 + lk * 4 + r;
        float v = acc[m][n][r] + bb;
        if (OUT_BF16) ((unsigned short*)Cout)[(size_t)row * N + col] = f2b(v);
        else          ((float*)Cout)[(size_t)row * N + col] = v;
      }
    }
  }
}

// ---------------- RoPE (q heads + k); q pre-scaled by 1/sqrt(D) ----------------
__global__ void k_rope(const unsigned short* __restrict__ qkv,
                       unsigned short* __restrict__ qr,
                       unsigned short* __restrict__ kr,
                       int S, int H) {
  int R = blockIdx.x * 4 + (threadIdx.x >> 6);
  int lane = threadIdx.x & 63;
  int per_b = S * (H + 1);
  int b = R / per_b;
  int rem = R - b * per_b;
  int s = rem / (H + 1);
  int j = rem - s * (H + 1);
  const unsigned short* src = qkv + (size_t)(b * S + s) * 2304 + (j < H ? j * 128 : 2048);
  float x1 = b2f(src[lane]);
  float x2 = b2f(src[lane + 64]);
  float invf = expf(-(float)lane * (9.210340371976184f / 64.0f));
  float ang = (float)s * invf;
  float c = cosf(ang), sn = sinf(ang);
  float o1 = x1 * c - x2 * sn;
  float o2 = x1 * sn + x2 * c;
  unsigned short* dst;
  if (j < H) {
    const float scale = 0.08838834764831845f;
    o1 *= scale; o2 *= scale;
    dst = qr + ((size_t)(b * H + j) * S + s) * 128;
  } else {
    dst = kr + ((size_t)(b * S) + s) * 128;
  }
  dst[lane]      = f2b(o1);
  dst[lane + 64] = f2b(o2);
}

// ---------------- V transpose ----------------
__global__ void k_vtrans(const unsigned short* __restrict__ qkv,
                         unsigned short* __restrict__ vt, int S) {
  __shared__ unsigned short tile[32][33];
  int b = blockIdx.z;
  int s0 = blockIdx.x * 32, d0 = blockIdx.y * 32;
  int tx = threadIdx.x & 31, ty = threadIdx.x >> 5;
  for (int yy = ty; yy < 32; yy += 8)
    tile[yy][tx] = qkv[(size_t)(b * S + s0 + yy) * 2304 + 2176 + d0 + tx];
  __syncthreads();
  for (int yy = ty; yy < 32; yy += 8)
    vt[((size_t)b * 128 + d0 + yy) * S + s0 + tx] = tile[tx][yy];
}

// ---------------- causal flash attention (balanced block split + reuse) ----------------
// r10's verified 2-group compute body (32 q-rows/wave, K/V LDS fragments reused,
// permuted-K swapped QK^T, lane-local P). Work split: pair (qtA=8+p, qtB=7-p)
// has nA+nB=34 kv-passes; half 0 = A passes 0..16, half 1 = A 17..nA-1 then all
// of B -- every block exactly 17 passes. A-partials (additive, no-max softmax)
// -> bf16 scratch + f32 lsum scratch; combined by k_combine. B stored directly.
// flat-id decode: co-resident blocks (flat, flat+256) = two halves of same pair.
__global__ __launch_bounds__(256, 2)
void k_attn(const unsigned short* __restrict__ qr,  // [B][H][S][128]
            const unsigned short* __restrict__ kr,  // [B][S][128]
            const unsigned short* __restrict__ vt,  // [B][128][S]
            unsigned short* __restrict__ attn_out,  // [B][S][2048]
            unsigned short* __restrict__ pscr,      // [pg][2][128][128] bf16
            float* __restrict__ lscr,               // [pg][2][128]
            int S, int H) {
  const int flat = blockIdx.x + 16 * blockIdx.y + 256 * blockIdx.z;
  const int half = flat >> 8;
  const int p    = flat & 7;
  const int h    = (flat >> 3) & 15;
  const int b    = (flat >> 7) & 1;
  const int qtA = 8 + p, qtB = 7 - p;
  const int qb0A = qtA * 128, qb0B = qtB * 128;
  const int nA = 2 * qtA + 2;                 // 18..32
  const int pg = (b * H + h) * 8 + p;

  const int tid = threadIdx.x, wid = tid >> 6, lane = tid & 63;
  const int lr = lane & 15, lk = lane >> 4;

  __shared__ unsigned short Kt[2][64 * 128];   // 16KB each
  __shared__ unsigned short Vt[2][128 * 64];   // 16KB each

  const char* kbyte = (const char*)(kr + (size_t)b * S * 128);
  const char* vbyte = (const char*)(vt + (size_t)b * 128 * S);
  const size_t vrow_bytes = (size_t)S * 2;

  bf16x8 aq[2][4];
  auto loadQ = [&](int qb0) {
    #pragma unroll
    for (int g = 0; g < 2; ++g) {
      const unsigned short* qptr = qr + ((size_t)(b * H + h) * S + (qb0 + wid * 32 + g * 16 + lr)) * 128;
      #pragma unroll
      for (int kk = 0; kk < 4; ++kk) aq[g][kk] = *(const bf16x8*)(qptr + kk * 32 + lk * 8);
    }
  };

  f32x4 acc[2][8];
  float ls[2];
  auto resetAcc = [&]() {
    #pragma unroll
    for (int g = 0; g < 2; ++g) {
      ls[g] = 0.f;
      #pragma unroll
      for (int t = 0; t < 8; ++t) acc[g][t] = (f32x4){0.f, 0.f, 0.f, 0.f};
    }
  };

  const int vsw = ((lr & 3) | ((lr >> 1) & 4)) << 4;
  int krow_[4], ksw_[4];
  #pragma unroll
  for (int m = 0; m < 4; ++m) {
    int row = ((m >> 1) << 5) + ((m & 1) << 2) + ((lr >> 2) << 3) + (lr & 3);
    krow_[m] = row;
    ksw_[m] = ((row & 3) | ((row >> 1) & 4)) << 4;
  }

  auto stage = [&](int buf, int kb) {
    const char* kg = kbyte + (size_t)kb * 256;
    #pragma unroll
    for (int r = 0; r < 4; ++r) {
      int row = (tid >> 4) + r * 16;
      int sw = ((row & 3) | ((row >> 1) & 4)) << 4;
      const char* src = kg + row * 256 + (((tid & 15) << 4) ^ sw);
      gload_lds16(src, (void*)((char*)&Kt[buf][0] + r * 4096 + wid * 1024));
    }
    const char* vg = vbyte + (size_t)kb * 2;
    #pragma unroll
    for (int r = 0; r < 4; ++r) {
      int d = (tid >> 3) + r * 32;
      int sw = ((d & 3) | ((d >> 1) & 4)) << 4;
      const char* src = vg + (size_t)d * vrow_bytes + (((tid & 7) << 4) ^ sw);
      gload_lds16(src, (void*)((char*)&Vt[buf][0] + r * 4096 + wid * 1024));
    }
  };

  // item j (0..16) -> (kb, which tile)
  auto itemKb = [&](int j, int& which) -> int {
    int idx = half * 17 + j;
    if (idx < nA) { which = 0; return idx * 64; }
    which = 1; return (idx - nA) * 64;
  };

  // flush A partial to scratch
  auto flushA = [&]() {
    #pragma unroll
    for (int g = 0; g < 2; ++g) {
      float v = ls[g];
      v += __shfl_xor(v, 16);
      v += __shfl_xor(v, 32);
      if (lk == 0) lscr[((size_t)pg * 2 + half) * 128 + wid * 32 + g * 16 + lr] = v;
      #pragma unroll
      for (int t = 0; t < 8; ++t)
        #pragma unroll
        for (int r = 0; r < 4; ++r) {
          int row = wid * 32 + g * 16 + lk * 4 + r;
          pscr[((size_t)pg * 2 + half) * 16384 + row * 128 + t * 16 + lr] = f2b(acc[g][t][r]);
        }
    }
  };

  auto computeTile = [&](int cur, int kb, int qb0cur) {
    const int qw = qb0cur + wid * 32;
    if (kb > qw + 31) return;
    const unsigned short* Kc = &Kt[cur][0];
    const unsigned short* Vc = &Vt[cur][0];
    f32x4 s4[2][4];
    #pragma unroll
    for (int g = 0; g < 2; ++g)
      #pragma unroll
      for (int m = 0; m < 4; ++m) s4[g][m] = (f32x4){0.f, 0.f, 0.f, 0.f};
    __builtin_amdgcn_s_setprio(1);
    #pragma unroll
    for (int kk = 0; kk < 4; ++kk) {
      bf16x8 kfk[4];
      #pragma unroll
      for (int m = 0; m < 4; ++m)
        kfk[m] = *(const bf16x8*)((const char*)Kc + krow_[m] * 256 + ((kk * 64 + lk * 16) ^ ksw_[m]));
      #pragma unroll
      for (int m = 0; m < 4; ++m) {
        s4[0][m] = __builtin_amdgcn_mfma_f32_16x16x32_bf16(kfk[m], aq[0][kk], s4[0][m], 0, 0, 0);
        s4[1][m] = __builtin_amdgcn_mfma_f32_16x16x32_bf16(kfk[m], aq[1][kk], s4[1][m], 0, 0, 0);
      }
    }
    __builtin_amdgcn_s_setprio(0);
    bf16x8 pa[2][2];
    #pragma unroll
    for (int g = 0; g < 2; ++g) {
      const int rowq = qw + g * 16 + lr;
      const bool domask = (kb + 64) > (qw + g * 16);
      uint2 pk[4];
      #pragma unroll
      for (int m = 0; m < 4; ++m) {
        const int kb_m = kb + ((m >> 1) << 5) + ((m & 1) << 2) + lk * 8;
        float pv[4];
        #pragma unroll
        for (int r = 0; r < 4; ++r) {
          float v = __expf(s4[g][m][r]);
          if (domask && (kb_m + r) > rowq) v = 0.f;
          pv[r] = v;
          ls[g] += v;
        }
        pk[m].x = pkcvt(pv[0], pv[1]);
        pk[m].y = pkcvt(pv[2], pv[3]);
      }
      uint4 ua, ub;
      ua.x = pk[0].x; ua.y = pk[0].y; ua.z = pk[1].x; ua.w = pk[1].y;
      ub.x = pk[2].x; ub.y = pk[2].y; ub.z = pk[3].x; ub.w = pk[3].y;
      pa[g][0] = __builtin_bit_cast(bf16x8, ua);
      pa[g][1] = __builtin_bit_cast(bf16x8, ub);
    }
    __builtin_amdgcn_s_setprio(1);
    #pragma unroll
    for (int t = 0; t < 8; ++t) {
      const char* vl = (const char*)(Vc + (t * 16 + lr) * 64);
      bf16x8 bv0 = *(const bf16x8*)(vl + ((lk * 16) ^ vsw));
      bf16x8 bv1 = *(const bf16x8*)(vl + ((64 + lk * 16) ^ vsw));
      acc[0][t] = __builtin_amdgcn_mfma_f32_16x16x32_bf16(pa[0][0], bv0, acc[0][t], 0, 0, 0);
      acc[1][t] = __builtin_amdgcn_mfma_f32_16x16x32_bf16(pa[1][0], bv0, acc[1][t], 0, 0, 0);
      acc[0][t] = __builtin_amdgcn_mfma_f32_16x16x32_bf16(pa[0][1], bv1, acc[0][t], 0, 0, 0);
      acc[1][t] = __builtin_amdgcn_mfma_f32_16x16x32_bf16(pa[1][1], bv1, acc[1][t], 0, 0, 0);
    }
    __builtin_amdgcn_s_setprio(0);
  };

  loadQ(qb0A);
  resetAcc();
  int curTile = 0, qb0cur = qb0A;

  {
    int wh0;
    stage(0, itemKb(0, wh0));
  }
  int cur = 0;
  #pragma unroll 1
  for (int j = 0; j < 17; ++j) {
    if (j + 1 < 17) {
      int whn;
      stage(cur ^ 1, itemKb(j + 1, whn));
      asm volatile("s_waitcnt vmcnt(8)" ::: "memory");
    } else {
      asm volatile("s_waitcnt vmcnt(0)" ::: "memory");
    }
    __builtin_amdgcn_sched_barrier(0);
    __builtin_amdgcn_s_barrier();
    int wh;
    const int kb = itemKb(j, wh);
    if (wh != curTile) {            // block-uniform switch A -> B (half 1 only)
      flushA();
      resetAcc();
      loadQ(qb0B);
      curTile = 1;
      qb0cur = qb0B;
    }
    computeTile(cur, kb, qb0cur);
    __builtin_amdgcn_s_barrier();
    cur ^= 1;
  }

  if (half == 0) {
    flushA();                       // A partial (half 0)
  } else {
    // B complete: normalize and store directly
    #pragma unroll
    for (int g = 0; g < 2; ++g) {
      float v = ls[g];
      v += __shfl_xor(v, 16);
      v += __shfl_xor(v, 32);
      float rl[4];
      #pragma unroll
      for (int r = 0; r < 4; ++r) rl[r] = 1.0f / __shfl(v, lk * 4 + r);
      #pragma unroll
      for (int t = 0; t < 8; ++t) {
        #pragma unroll
        for (int r = 0; r < 4; ++r) {
          int srow = qb0B + wid * 32 + g * 16 + lk * 4 + r;
          float o = acc[g][t][r] * rl[r];
          attn_out[((size_t)(b * S) + srow) * 2048 + h * 128 + t * 16 + lr] = f2b(o);
        }
      }
    }
  }
}

// ---------------- combine A partials ----------------
__global__ void k_combine(const unsigned short* __restrict__ pscr,
                          const float* __restrict__ lscr,
                          unsigned short* __restrict__ attn_out, int S, int H) {
  const int p = blockIdx.x, h = blockIdx.y, b = blockIdx.z;
  const int pg = (b * H + h) * 8 + p;
  const int qb0A = (8 + p) * 128;
  const int tid = threadIdx.x;
  const unsigned short* p0 = pscr + (size_t)pg * 2 * 16384;
  const unsigned short* p1 = p0 + 16384;
  const float* l0 = lscr + (size_t)pg * 2 * 128;
  const float* l1 = l0 + 128;
  #pragma unroll
  for (int it = 0; it < 8; ++it) {
    int row = it * 16 + (tid >> 4);
    int col = (tid & 15) * 8;
    float rl = 1.0f / (l0[row] + l1[row]);
    ushort4 a = *(const ushort4*)(p0 + row * 128 + col);
    ushort4 c = *(const ushort4*)(p1 + row * 128 + col);
    ushort4 a2 = *(const ushort4*)(p0 + row * 128 + col + 4);
    ushort4 c2 = *(const ushort4*)(p1 + row * 128 + col + 4);
    ushort4 o1, o2;
    o1.x = f2b((b2f(a.x) + b2f(c.x)) * rl);
    o1.y = f2b((b2f(a.y) + b2f(c.y)) * rl);
    o1.z = f2b((b2f(a.z) + b2f(c.z)) * rl);
    o1.w = f2b((b2f(a.w) + b2f(c.w)) * rl);
    o2.x = f2b((b2f(a2.x) + b2f(c2.x)) * rl);
    o2.y = f2b((b2f(a2.y) + b2f(c2.y)) * rl);
    o2.z = f2b((b2f(a2.z) + b2f(c2.z)) * rl);
    o2.w = f2b((b2f(a2.w) + b2f(c2.w)) * rl);
    unsigned short* dst = attn_out + ((size_t)(b * S) + qb0A + row) * 2048 + h * 128 + col;
    *(ushort4*)dst = o1;
    *(ushort4*)(dst + 4) = o2;
  }
}

// ---------------- launch ----------------
extern "C" void kernel_launch(void* const* d_in, const int* in_sizes, int n_in,
                              void* d_out, int out_size, void* d_ws, size_t ws_size,
                              hipStream_t stream) {
  const float* x  = (const float*)d_in[0];
  const float* Wq = (const float*)d_in[1];
  const float* bq = (const float*)d_in[2];
  const float* Wk = (const float*)d_in[3];
  const float* bk = (const float*)d_in[4];
  const float* Wv = (const float*)d_in[5];
  const float* bv = (const float*)d_in[6];
  const float* Wo = (const float*)d_in[7];
  const float* bo = (const float*)d_in[8];

  const int B = 2, S = 2048, E = 2048, H = 16, D = 128;
  const int M = B * S;             // 4096
  const int Nqkv = H * D + 2 * D;  // 2304

  char* w = (char*)d_ws;
  unsigned short* xb    = (unsigned short*)w;                              // 16,777,216 B
  unsigned short* WqkvT = (unsigned short*)(w + 16777216);                 //  9,437,184 B
  unsigned short* qkv   = (unsigned short*)(w + 16777216 + 9437184);       // 18,874,368 B
  unsigned short* qr    = (unsigned short*)(w + 16777216 + 9437184 + 18874368); // 16,777,216 B
  unsigned short* kr    = qr + (size_t)B * H * S * D;
  unsigned short* vtb   = kr + (size_t)B * S * D;
  float*          cbias = (float*)(vtb + (size_t)B * S * D);   // unused (kept for layout)
  unsigned short* WoT   = (unsigned short*)(cbias + 4096);
  unsigned short* attn_out = xb;       // alias: xb dead after gemm1
  unsigned short* pscr  = qkv;         // alias: qkv dead after rope+vtrans (16.8MB)
  float*          lscr  = (float*)WqkvT;  // alias: WqkvT dead after gemm1 (256KB)

  k_cvt_bf16<<<dim3((M * E / 4) / 256), 256, 0, stream>>>(x, xb, M * E / 4);
  k_transpose<<<dim3(Nqkv / 32, E / 32, 2), 256, 0, stream>>>(Wq, Wk, Wv, Wo, WqkvT, WoT);
  k_gemm_lds<1, 1><<<dim3(Nqkv / 128, M / 128), 256, 0, stream>>>(xb, WqkvT, bq, bk, bv, (void*)qkv, M, Nqkv, E);
  k_rope<<<dim3(B * S * (H + 1) / 4), 256, 0, stream>>>(qkv, qr, kr, S, H);
  k_vtrans<<<dim3(S / 32, D / 32, B), 256, 0, stream>>>(qkv, vtb, S);
  k_attn<<<dim3(16, 16, 2), 256, 0, stream>>>(qr, kr, vtb, attn_out, pscr, lscr, S, H);
  k_combine<<<dim3(8, H, B), 256, 0, stream>>>(pscr, lscr, attn_out, S, H);
  k_gemm_lds<0, 0><<<dim3(E / 128, M / 128), 256, 0, stream>>>(attn_out, WoT, bo, nullptr, nullptr, (void*)d_out, M, E, H * D);
}

// Round 16
// 195.455 us; speedup vs baseline: 1.2119x; 1.0049x over previous
//
#include <hip/hip_runtime.h>
#include <stdint.h>

typedef __bf16 bf16x8 __attribute__((ext_vector_type(8)));
typedef __bf16 bf16x2 __attribute__((ext_vector_type(2)));
typedef float  f32x4  __attribute__((ext_vector_type(4)));
typedef short  s16x8  __attribute__((ext_vector_type(8)));

__device__ inline unsigned short f2b(float f) {
  unsigned int u = __builtin_bit_cast(unsigned int, f);
  u += 0x7FFFu + ((u >> 16) & 1u);
  return (unsigned short)(u >> 16);
}
__device__ inline float b2f(unsigned short h) {
  unsigned int u = ((unsigned int)h) << 16;
  return __builtin_bit_cast(float, u);
}
__device__ inline unsigned int pkcvt(float a, float b) {
  bf16x2 t;
  t[0] = (__bf16)a;
  t[1] = (__bf16)b;
  return __builtin_bit_cast(unsigned int, t);
}
__device__ inline void gload_lds16(const void* g, void* l) {
  __builtin_amdgcn_global_load_lds(
      (const __attribute__((address_space(1))) unsigned int*)g,
      (__attribute__((address_space(3))) unsigned int*)l, 16, 0, 0);
}

// ---------------- elementwise f32 -> bf16 ----------------
__global__ void k_cvt_bf16(const float* __restrict__ in, unsigned short* __restrict__ out, int n4) {
  int i = blockIdx.x * blockDim.x + threadIdx.x;
  if (i < n4) {
    float4 v = ((const float4*)in)[i];
    ushort4 o;
    o.x = f2b(v.x); o.y = f2b(v.y); o.z = f2b(v.z); o.w = f2b(v.w);
    ((ushort4*)out)[i] = o;
  }
}

// ---------------- transpose f32 -> bf16 [N][K]; z=0: Wq|Wk|Wv concat, z=1: Wo ----------------
__global__ void k_transpose(const float* __restrict__ Wq, const float* __restrict__ Wk,
                            const float* __restrict__ Wv, const float* __restrict__ Wo,
                            unsigned short* __restrict__ dstQKV, unsigned short* __restrict__ dstO) {
  __shared__ float tile[32][33];
  int n0 = blockIdx.x * 32;
  int k0 = blockIdx.y * 32;
  const float* src; int ldn, noff, K;
  unsigned short* dst;
  if (blockIdx.z == 0) {
    K = 2048; dst = dstQKV;
    if (n0 < 2048)       { src = Wq; ldn = 2048; noff = n0; }
    else if (n0 < 2176)  { src = Wk; ldn = 128;  noff = n0 - 2048; }
    else                 { src = Wv; ldn = 128;  noff = n0 - 2176; }
  } else {
    if (n0 >= 2048) return;
    K = 2048; dst = dstO;
    src = Wo; ldn = 2048; noff = n0;
  }
  int tx = threadIdx.x & 31, ty = threadIdx.x >> 5;
  for (int yy = ty; yy < 32; yy += 8)
    tile[yy][tx] = src[(size_t)(k0 + yy) * ldn + noff + tx];
  __syncthreads();
  for (int yy = ty; yy < 32; yy += 8)
    dst[(size_t)(n0 + yy) * K + k0 + tx] = f2b(tile[tx][yy]);
}

// ---------------- bf16 GEMM, 128x96 tile (GEMM1: balanced 768 = 3/CU) ----------------
// BK=32, gload_lds w16, 3-buffer ring, 2-deep prefetch, counted vmcnt
// (wave-uniform counts: waves 0-2 stage A+B, wave 3 A only), XCD swizzle.
template<int BIAS3>
__global__ __launch_bounds__(256)
void k_gemm96(const unsigned short* __restrict__ A, const unsigned short* __restrict__ Bt,
              const float* __restrict__ b0, const float* __restrict__ b1,
              const float* __restrict__ b2, unsigned short* __restrict__ Cout,
              int M, int N, int K) {
  __shared__ unsigned short As[3][4096];   // 128x32
  __shared__ unsigned short Bs[3][3072];   // 96x32
  const int tid  = threadIdx.x;
  const int lane = tid & 63, wid = tid >> 6;
  const int lr = lane & 15, lk = lane >> 4;
  const int wr = wid >> 1,  wc = wid & 1;

  const int nwg = gridDim.x * gridDim.y;
  const int flat = blockIdx.y * gridDim.x + blockIdx.x;
  const int swz = (flat & 7) * (nwg >> 3) + (flat >> 3);
  const int mb = (swz / gridDim.x) * 128;
  const int nb = (swz % gridDim.x) * 96;

  // A staging: each thread 2 chunks (rows tid>>2 and +64)
  const int srow = tid >> 2, scb = (tid & 3) * 8;
  const size_t gA = (size_t)(mb + srow) * K + scb;
  // B staging (wid<3): rows wid*32 + r*16 + (lane>>2), col (lane&3)*8
  const int brow0 = wid * 32 + (lane >> 2);
  const int bcol  = (lane & 3) * 8;
  const size_t gB = (size_t)(nb + brow0) * K + bcol;
  const int bdst0 = (wid * 128 + lane) * 16;   // byte offset of chunk, +64*16 for r=1

  f32x4 acc[4][3];
  #pragma unroll
  for (int i = 0; i < 4; ++i)
    #pragma unroll
    for (int j = 0; j < 3; ++j) acc[i][j] = (f32x4){0.f, 0.f, 0.f, 0.f};

  auto stage = [&](int buf, int kt) {
    const size_t ko = (size_t)kt * 32;
    gload_lds16(A + gA + ko,                  &As[buf][(tid) * 8]);
    gload_lds16(A + gA + 64 * (size_t)K + ko, &As[buf][2048 + tid * 8]);
    if (wid < 3) {
      gload_lds16(Bt + gB + ko,                  (char*)&Bs[buf][0] + bdst0);
      gload_lds16(Bt + gB + 16 * (size_t)K + ko, (char*)&Bs[buf][0] + bdst0 + 1024);
    }
  };

  const int ktn = K >> 5;
  stage(0, 0);
  stage(1, 1);

  int cur = 0;
  #pragma unroll 1
  for (int kt = 0; kt < ktn; ++kt) {
    if (kt + 2 < ktn) {
      int nbuf = cur + 2; if (nbuf >= 3) nbuf -= 3;
      stage(nbuf, kt + 2);
      if (wid < 3) asm volatile("s_waitcnt vmcnt(8)" ::: "memory");
      else         asm volatile("s_waitcnt vmcnt(4)" ::: "memory");
    } else if (kt + 1 < ktn) {
      if (wid < 3) asm volatile("s_waitcnt vmcnt(4)" ::: "memory");
      else         asm volatile("s_waitcnt vmcnt(2)" ::: "memory");
    } else {
      asm volatile("s_waitcnt vmcnt(0)" ::: "memory");
    }
    __builtin_amdgcn_sched_barrier(0);
    __builtin_amdgcn_s_barrier();
    bf16x8 af[4], bfv[3];
    #pragma unroll
    for (int m = 0; m < 4; ++m)
      af[m]  = *(const bf16x8*)&As[cur][(wr * 64 + m * 16 + lr) * 32 + lk * 8];
    #pragma unroll
    for (int n = 0; n < 3; ++n)
      bfv[n] = *(const bf16x8*)&Bs[cur][(wc * 48 + n * 16 + lr) * 32 + lk * 8];
    #pragma unroll
    for (int m = 0; m < 4; ++m)
      #pragma unroll
      for (int n = 0; n < 3; ++n)
        acc[m][n] = __builtin_amdgcn_mfma_f32_16x16x32_bf16(af[m], bfv[n], acc[m][n], 0, 0, 0);
    __builtin_amdgcn_s_barrier();
    ++cur; if (cur == 3) cur = 0;
  }

  const int r0 = mb + wr * 64, c0 = nb + wc * 48;
  #pragma unroll
  for (int m = 0; m < 4; ++m) {
    #pragma unroll
    for (int n = 0; n < 3; ++n) {
      int col = c0 + n * 16 + lr;
      float bb;
      if (BIAS3) bb = (col < 2048) ? b0[col] : (col < 2176 ? b1[col - 2048] : b2[col - 2176]);
      else       bb = b0[col];
      #pragma unroll
      for (int r = 0; r < 4; ++r) {
        int row = r0 + m * 16 + lk * 4 + r;
        Cout[(size_t)row * N + col] = f2b(acc[m][n][r] + bb);
      }
    }
  }
}

// ---------------- bf16 GEMM: C = A * Bt^T + bias (r14 verified, 128x128) ----------------
template<int OUT_BF16, int BIAS3>
__global__ __launch_bounds__(256)
void k_gemm_lds(const unsigned short* __restrict__ A, const unsigned short* __restrict__ Bt,
                const float* __restrict__ b0, const float* __restrict__ b1,
                const float* __restrict__ b2, void* __restrict__ Cout,
                int M, int N, int K) {
  __shared__ unsigned short As[3][4096];
  __shared__ unsigned short Bs[3][4096];
  const int tid  = threadIdx.x;
  const int lane = tid & 63, wid = tid >> 6;
  const int lr = lane & 15, lk = lane >> 4;
  const int wr = wid >> 1,  wc = wid & 1;

  const int nwg = gridDim.x * gridDim.y;
  const int flat = blockIdx.y * gridDim.x + blockIdx.x;
  const int swz = (flat & 7) * (nwg >> 3) + (flat >> 3);
  const int mb = (swz / gridDim.x) * 128;
  const int nb = (swz % gridDim.x) * 128;

  const int srow = tid >> 2, scb = (tid & 3) * 8;
  const size_t gA = (size_t)(mb + srow) * K + scb;
  const size_t gB = (size_t)(nb + srow) * K + scb;
  const int ldso = wid * 512;

  f32x4 acc[4][4];
  #pragma unroll
  for (int i = 0; i < 4; ++i)
    #pragma unroll
    for (int j = 0; j < 4; ++j) acc[i][j] = (f32x4){0.f, 0.f, 0.f, 0.f};

  auto stage = [&](int buf, int kt) {
    const size_t ko = (size_t)kt * 32;
    gload_lds16(A  + gA + ko,                  &As[buf][ldso]);
    gload_lds16(A  + gA + 64 * (size_t)K + ko, &As[buf][2048 + ldso]);
    gload_lds16(Bt + gB + ko,                  &Bs[buf][ldso]);
    gload_lds16(Bt + gB + 64 * (size_t)K + ko, &Bs[buf][2048 + ldso]);
  };

  const int ktn = K >> 5;
  stage(0, 0);
  stage(1, 1);

  int cur = 0;
  #pragma unroll 1
  for (int kt = 0; kt < ktn; ++kt) {
    if (kt + 2 < ktn) {
      int nbuf = cur + 2; if (nbuf >= 3) nbuf -= 3;
      stage(nbuf, kt + 2);
      asm volatile("s_waitcnt vmcnt(8)" ::: "memory");
    } else if (kt + 1 < ktn) {
      asm volatile("s_waitcnt vmcnt(4)" ::: "memory");
    } else {
      asm volatile("s_waitcnt vmcnt(0)" ::: "memory");
    }
    __builtin_amdgcn_sched_barrier(0);
    __builtin_amdgcn_s_barrier();
    bf16x8 af[4], bfv[4];
    #pragma unroll
    for (int m = 0; m < 4; ++m)
      af[m]  = *(const bf16x8*)&As[cur][(wr * 64 + m * 16 + lr) * 32 + lk * 8];
    #pragma unroll
    for (int n = 0; n < 4; ++n)
      bfv[n] = *(const bf16x8*)&Bs[cur][(wc * 64 + n * 16 + lr) * 32 + lk * 8];
    #pragma unroll
    for (int m = 0; m < 4; ++m)
      #pragma unroll
      for (int n = 0; n < 4; ++n)
        acc[m][n] = __builtin_amdgcn_mfma_f32_16x16x32_bf16(af[m], bfv[n], acc[m][n], 0, 0, 0);
    __builtin_amdgcn_s_barrier();
    ++cur; if (cur == 3) cur = 0;
  }

  const int r0 = mb + wr * 64, c0 = nb + wc * 64;
  #pragma unroll
  for (int m = 0; m < 4; ++m) {
    #pragma unroll
    for (int n = 0; n < 4; ++n) {
      int col = c0 + n * 16 + lr;
      float bb;
      if (BIAS3) bb = (col < 2048) ? b0[col] : (col < 2176 ? b1[col - 2048] : b2[col - 2176]);
      else       bb = b0[col];
      #pragma unroll
      for (int r = 0; r < 4; ++r) {
        int row = r0 + m * 16 + lk * 4 + r;
        float v = acc[m][n][r] + bb;
        if (OUT_BF16) ((unsigned short*)Cout)[(size_t)row * N + col] = f2b(v);
        else          ((float*)Cout)[(size_t)row * N + col] = v;
      }
    }
  }
}

// ---------------- RoPE (q heads + k); q pre-scaled by 1/sqrt(D) ----------------
__global__ void k_rope(const unsigned short* __restrict__ qkv,
                       unsigned short* __restrict__ qr,
                       unsigned short* __restrict__ kr,
                       int S, int H) {
  int R = blockIdx.x * 4 + (threadIdx.x >> 6);
  int lane = threadIdx.x & 63;
  int per_b = S * (H + 1);
  int b = R / per_b;
  int rem = R - b * per_b;
  int s = rem / (H + 1);
  int j = rem - s * (H + 1);
  const unsigned short* src = qkv + (size_t)(b * S + s) * 2304 + (j < H ? j * 128 : 2048);
  float x1 = b2f(src[lane]);
  float x2 = b2f(src[lane + 64]);
  float invf = expf(-(float)lane * (9.210340371976184f / 64.0f));
  float ang = (float)s * invf;
  float c = cosf(ang), sn = sinf(ang);
  float o1 = x1 * c - x2 * sn;
  float o2 = x1 * sn + x2 * c;
  unsigned short* dst;
  if (j < H) {
    const float scale = 0.08838834764831845f;
    o1 *= scale; o2 *= scale;
    dst = qr + ((size_t)(b * H + j) * S + s) * 128;
  } else {
    dst = kr + ((size_t)(b * S) + s) * 128;
  }
  dst[lane]      = f2b(o1);
  dst[lane + 64] = f2b(o2);
}

// ---------------- V transpose ----------------
__global__ void k_vtrans(const unsigned short* __restrict__ qkv,
                         unsigned short* __restrict__ vt, int S) {
  __shared__ unsigned short tile[32][33];
  int b = blockIdx.z;
  int s0 = blockIdx.x * 32, d0 = blockIdx.y * 32;
  int tx = threadIdx.x & 31, ty = threadIdx.x >> 5;
  for (int yy = ty; yy < 32; yy += 8)
    tile[yy][tx] = qkv[(size_t)(b * S + s0 + yy) * 2304 + 2176 + d0 + tx];
  __syncthreads();
  for (int yy = ty; yy < 32; yy += 8)
    vt[((size_t)b * 128 + d0 + yy) * S + s0 + tx] = tile[tx][yy];
}

// ---------------- causal flash attention (r15 verified: balanced split + reuse) ----------------
__global__ __launch_bounds__(256, 2)
void k_attn(const unsigned short* __restrict__ qr,
            const unsigned short* __restrict__ kr,
            const unsigned short* __restrict__ vt,
            unsigned short* __restrict__ attn_out,
            unsigned short* __restrict__ pscr,
            float* __restrict__ lscr,
            int S, int H) {
  const int flat = blockIdx.x + 16 * blockIdx.y + 256 * blockIdx.z;
  const int half = flat >> 8;
  const int p    = flat & 7;
  const int h    = (flat >> 3) & 15;
  const int b    = (flat >> 7) & 1;
  const int qtA = 8 + p, qtB = 7 - p;
  const int qb0A = qtA * 128, qb0B = qtB * 128;
  const int nA = 2 * qtA + 2;
  const int pg = (b * H + h) * 8 + p;

  const int tid = threadIdx.x, wid = tid >> 6, lane = tid & 63;
  const int lr = lane & 15, lk = lane >> 4;

  __shared__ unsigned short Kt[2][64 * 128];
  __shared__ unsigned short Vt[2][128 * 64];

  const char* kbyte = (const char*)(kr + (size_t)b * S * 128);
  const char* vbyte = (const char*)(vt + (size_t)b * 128 * S);
  const size_t vrow_bytes = (size_t)S * 2;

  bf16x8 aq[2][4];
  auto loadQ = [&](int qb0) {
    #pragma unroll
    for (int g = 0; g < 2; ++g) {
      const unsigned short* qptr = qr + ((size_t)(b * H + h) * S + (qb0 + wid * 32 + g * 16 + lr)) * 128;
      #pragma unroll
      for (int kk = 0; kk < 4; ++kk) aq[g][kk] = *(const bf16x8*)(qptr + kk * 32 + lk * 8);
    }
  };

  f32x4 acc[2][8];
  float ls[2];
  auto resetAcc = [&]() {
    #pragma unroll
    for (int g = 0; g < 2; ++g) {
      ls[g] = 0.f;
      #pragma unroll
      for (int t = 0; t < 8; ++t) acc[g][t] = (f32x4){0.f, 0.f, 0.f, 0.f};
    }
  };

  const int vsw = ((lr & 3) | ((lr >> 1) & 4)) << 4;
  int krow_[4], ksw_[4];
  #pragma unroll
  for (int m = 0; m < 4; ++m) {
    int row = ((m >> 1) << 5) + ((m & 1) << 2) + ((lr >> 2) << 3) + (lr & 3);
    krow_[m] = row;
    ksw_[m] = ((row & 3) | ((row >> 1) & 4)) << 4;
  }

  auto stage = [&](int buf, int kb) {
    const char* kg = kbyte + (size_t)kb * 256;
    #pragma unroll
    for (int r = 0; r < 4; ++r) {
      int row = (tid >> 4) + r * 16;
      int sw = ((row & 3) | ((row >> 1) & 4)) << 4;
      const char* src = kg + row * 256 + (((tid & 15) << 4) ^ sw);
      gload_lds16(src, (void*)((char*)&Kt[buf][0] + r * 4096 + wid * 1024));
    }
    const char* vg = vbyte + (size_t)kb * 2;
    #pragma unroll
    for (int r = 0; r < 4; ++r) {
      int d = (tid >> 3) + r * 32;
      int sw = ((d & 3) | ((d >> 1) & 4)) << 4;
      const char* src = vg + (size_t)d * vrow_bytes + (((tid & 7) << 4) ^ sw);
      gload_lds16(src, (void*)((char*)&Vt[buf][0] + r * 4096 + wid * 1024));
    }
  };

  auto itemKb = [&](int j, int& which) -> int {
    int idx = half * 17 + j;
    if (idx < nA) { which = 0; return idx * 64; }
    which = 1; return (idx - nA) * 64;
  };

  auto flushA = [&]() {
    #pragma unroll
    for (int g = 0; g < 2; ++g) {
      float v = ls[g];
      v += __shfl_xor(v, 16);
      v += __shfl_xor(v, 32);
      if (lk == 0) lscr[((size_t)pg * 2 + half) * 128 + wid * 32 + g * 16 + lr] = v;
      #pragma unroll
      for (int t = 0; t < 8; ++t)
        #pragma unroll
        for (int r = 0; r < 4; ++r) {
          int row = wid * 32 + g * 16 + lk * 4 + r;
          pscr[((size_t)pg * 2 + half) * 16384 + row * 128 + t * 16 + lr] = f2b(acc[g][t][r]);
        }
    }
  };

  auto computeTile = [&](int cur, int kb, int qb0cur) {
    const int qw = qb0cur + wid * 32;
    if (kb > qw + 31) return;
    const unsigned short* Kc = &Kt[cur][0];
    const unsigned short* Vc = &Vt[cur][0];
    f32x4 s4[2][4];
    #pragma unroll
    for (int g = 0; g < 2; ++g)
      #pragma unroll
      for (int m = 0; m < 4; ++m) s4[g][m] = (f32x4){0.f, 0.f, 0.f, 0.f};
    __builtin_amdgcn_s_setprio(1);
    #pragma unroll
    for (int kk = 0; kk < 4; ++kk) {
      bf16x8 kfk[4];
      #pragma unroll
      for (int m = 0; m < 4; ++m)
        kfk[m] = *(const bf16x8*)((const char*)Kc + krow_[m] * 256 + ((kk * 64 + lk * 16) ^ ksw_[m]));
      #pragma unroll
      for (int m = 0; m < 4; ++m) {
        s4[0][m] = __builtin_amdgcn_mfma_f32_16x16x32_bf16(kfk[m], aq[0][kk], s4[0][m], 0, 0, 0);
        s4[1][m] = __builtin_amdgcn_mfma_f32_16x16x32_bf16(kfk[m], aq[1][kk], s4[1][m], 0, 0, 0);
      }
    }
    __builtin_amdgcn_s_setprio(0);
    bf16x8 pa[2][2];
    #pragma unroll
    for (int g = 0; g < 2; ++g) {
      const int rowq = qw + g * 16 + lr;
      const bool domask = (kb + 64) > (qw + g * 16);
      uint2 pk[4];
      #pragma unroll
      for (int m = 0; m < 4; ++m) {
        const int kb_m = kb + ((m >> 1) << 5) + ((m & 1) << 2) + lk * 8;
        float pv[4];
        #pragma unroll
        for (int r = 0; r < 4; ++r) {
          float v = __expf(s4[g][m][r]);
          if (domask && (kb_m + r) > rowq) v = 0.f;
          pv[r] = v;
          ls[g] += v;
        }
        pk[m].x = pkcvt(pv[0], pv[1]);
        pk[m].y = pkcvt(pv[2], pv[3]);
      }
      uint4 ua, ub;
      ua.x = pk[0].x; ua.y = pk[0].y; ua.z = pk[1].x; ua.w = pk[1].y;
      ub.x = pk[2].x; ub.y = pk[2].y; ub.z = pk[3].x; ub.w = pk[3].y;
      pa[g][0] = __builtin_bit_cast(bf16x8, ua);
      pa[g][1] = __builtin_bit_cast(bf16x8, ub);
    }
    __builtin_amdgcn_s_setprio(1);
    #pragma unroll
    for (int t = 0; t < 8; ++t) {
      const char* vl = (const char*)(Vc + (t * 16 + lr) * 64);
      bf16x8 bv0 = *(const bf16x8*)(vl + ((lk * 16) ^ vsw));
      bf16x8 bv1 = *(const bf16x8*)(vl + ((64 + lk * 16) ^ vsw));
      acc[0][t] = __builtin_amdgcn_mfma_f32_16x16x32_bf16(pa[0][0], bv0, acc[0][t], 0, 0, 0);
      acc[1][t] = __builtin_amdgcn_mfma_f32_16x16x32_bf16(pa[1][0], bv0, acc[1][t], 0, 0, 0);
      acc[0][t] = __builtin_amdgcn_mfma_f32_16x16x32_bf16(pa[0][1], bv1, acc[0][t], 0, 0, 0);
      acc[1][t] = __builtin_amdgcn_mfma_f32_16x16x32_bf16(pa[1][1], bv1, acc[1][t], 0, 0, 0);
    }
    __builtin_amdgcn_s_setprio(0);
  };

  loadQ(qb0A);
  resetAcc();
  int curTile = 0, qb0cur = qb0A;

  {
    int wh0;
    stage(0, itemKb(0, wh0));
  }
  int cur = 0;
  #pragma unroll 1
  for (int j = 0; j < 17; ++j) {
    if (j + 1 < 17) {
      int whn;
      stage(cur ^ 1, itemKb(j + 1, whn));
      asm volatile("s_waitcnt vmcnt(8)" ::: "memory");
    } else {
      asm volatile("s_waitcnt vmcnt(0)" ::: "memory");
    }
    __builtin_amdgcn_sched_barrier(0);
    __builtin_amdgcn_s_barrier();
    int wh;
    const int kb = itemKb(j, wh);
    if (wh != curTile) {
      flushA();
      resetAcc();
      loadQ(qb0B);
      curTile = 1;
      qb0cur = qb0B;
    }
    computeTile(cur, kb, qb0cur);
    __builtin_amdgcn_s_barrier();
    cur ^= 1;
  }

  if (half == 0) {
    flushA();
  } else {
    #pragma unroll
    for (int g = 0; g < 2; ++g) {
      float v = ls[g];
      v += __shfl_xor(v, 16);
      v += __shfl_xor(v, 32);
      float rl[4];
      #pragma unroll
      for (int r = 0; r < 4; ++r) rl[r] = 1.0f / __shfl(v, lk * 4 + r);
      #pragma unroll
      for (int t = 0; t < 8; ++t) {
        #pragma unroll
        for (int r = 0; r < 4; ++r) {
          int srow = qb0B + wid * 32 + g * 16 + lk * 4 + r;
          float o = acc[g][t][r] * rl[r];
          attn_out[((size_t)(b * S) + srow) * 2048 + h * 128 + t * 16 + lr] = f2b(o);
        }
      }
    }
  }
}

// ---------------- combine A partials ----------------
__global__ void k_combine(const unsigned short* __restrict__ pscr,
                          const float* __restrict__ lscr,
                          unsigned short* __restrict__ attn_out, int S, int H) {
  const int p = blockIdx.x, h = blockIdx.y, b = blockIdx.z;
  const int pg = (b * H + h) * 8 + p;
  const int qb0A = (8 + p) * 128;
  const int tid = threadIdx.x;
  const unsigned short* p0 = pscr + (size_t)pg * 2 * 16384;
  const unsigned short* p1 = p0 + 16384;
  const float* l0 = lscr + (size_t)pg * 2 * 128;
  const float* l1 = l0 + 128;
  #pragma unroll
  for (int it = 0; it < 8; ++it) {
    int row = it * 16 + (tid >> 4);
    int col = (tid & 15) * 8;
    float rl = 1.0f / (l0[row] + l1[row]);
    ushort4 a = *(const ushort4*)(p0 + row * 128 + col);
    ushort4 c = *(const ushort4*)(p1 + row * 128 + col);
    ushort4 a2 = *(const ushort4*)(p0 + row * 128 + col + 4);
    ushort4 c2 = *(const ushort4*)(p1 + row * 128 + col + 4);
    ushort4 o1, o2;
    o1.x = f2b((b2f(a.x) + b2f(c.x)) * rl);
    o1.y = f2b((b2f(a.y) + b2f(c.y)) * rl);
    o1.z = f2b((b2f(a.z) + b2f(c.z)) * rl);
    o1.w = f2b((b2f(a.w) + b2f(c.w)) * rl);
    o2.x = f2b((b2f(a2.x) + b2f(c2.x)) * rl);
    o2.y = f2b((b2f(a2.y) + b2f(c2.y)) * rl);
    o2.z = f2b((b2f(a2.z) + b2f(c2.z)) * rl);
    o2.w = f2b((b2f(a2.w) + b2f(c2.w)) * rl);
    unsigned short* dst = attn_out + ((size_t)(b * S) + qb0A + row) * 2048 + h * 128 + col;
    *(ushort4*)dst = o1;
    *(ushort4*)(dst + 4) = o2;
  }
}

// ---------------- launch ----------------
extern "C" void kernel_launch(void* const* d_in, const int* in_sizes, int n_in,
                              void* d_out, int out_size, void* d_ws, size_t ws_size,
                              hipStream_t stream) {
  const float* x  = (const float*)d_in[0];
  const float* Wq = (const float*)d_in[1];
  const float* bq = (const float*)d_in[2];
  const float* Wk = (const float*)d_in[3];
  const float* bk = (const float*)d_in[4];
  const float* Wv = (const float*)d_in[5];
  const float* bv = (const float*)d_in[6];
  const float* Wo = (const float*)d_in[7];
  const float* bo = (const float*)d_in[8];

  const int B = 2, S = 2048, E = 2048, H = 16, D = 128;
  const int M = B * S;             // 4096
  const int Nqkv = H * D + 2 * D;  // 2304

  char* w = (char*)d_ws;
  unsigned short* xb    = (unsigned short*)w;
  unsigned short* WqkvT = (unsigned short*)(w + 16777216);
  unsigned short* qkv   = (unsigned short*)(w + 16777216 + 9437184);
  unsigned short* qr    = (unsigned short*)(w + 16777216 + 9437184 + 18874368);
  unsigned short* kr    = qr + (size_t)B * H * S * D;
  unsigned short* vtb   = kr + (size_t)B * S * D;
  float*          cbias = (float*)(vtb + (size_t)B * S * D);
  unsigned short* WoT   = (unsigned short*)(cbias + 4096);
  unsigned short* attn_out = xb;
  unsigned short* pscr  = qkv;
  float*          lscr  = (float*)WqkvT;

  k_cvt_bf16<<<dim3((M * E / 4) / 256), 256, 0, stream>>>(x, xb, M * E / 4);
  k_transpose<<<dim3(Nqkv / 32, E / 32, 2), 256, 0, stream>>>(Wq, Wk, Wv, Wo, WqkvT, WoT);
  k_gemm96<1><<<dim3(Nqkv / 96, M / 128), 256, 0, stream>>>(xb, WqkvT, bq, bk, bv, qkv, M, Nqkv, E);
  k_rope<<<dim3(B * S * (H + 1) / 4), 256, 0, stream>>>(qkv, qr, kr, S, H);
  k_vtrans<<<dim3(S / 32, D / 32, B), 256, 0, stream>>>(qkv, vtb, S);
  k_attn<<<dim3(16, 16, 2), 256, 0, stream>>>(qr, kr, vtb, attn_out, pscr, lscr, S, H);
  k_combine<<<dim3(8, H, B), 256, 0, stream>>>(pscr, lscr, attn_out, S, H);
  k_gemm_lds<0, 0><<<dim3(E / 128, M / 128), 256, 0, stream>>>(attn_out, WoT, bo, nullptr, nullptr, (void*)d_out, M, E, H * D);
}